// Round 4
// baseline (248.217 us; speedup 1.0000x reference)
//
#include <hip/hip_runtime.h>

constexpr int N  = 100000;
constexpr int E  = 1600000;
constexpr int IN = 128, HID = 64, OUTC = 32;

// coarse radix partition params (R6-proven)
constexpr int SHIFT = 9;                       // 512 nodes per bucket
constexpr int NPB   = 1 << SHIFT;              // 512
constexpr int NB    = (N + NPB - 1) / NPB;     // 196 buckets
constexpr int CAP   = 16384;                   // LDS stage cap (mean 8163, sigma~90)
constexpr int PB    = 800;                     // partition blocks (3 blocks/CU)
constexpr int CHUNK = E / PB;                  // 2000 (exact)
constexpr int HB    = 256;                     // hist blocks (gmat columns)

// ---- bf16 helpers ----
__device__ __forceinline__ unsigned short f2bf(float f) {
    union { float f; unsigned int u; } v; v.f = f;
    unsigned int u = v.u;
    return (unsigned short)((u + 0x7fffu + ((u >> 16) & 1u)) >> 16);
}
__device__ __forceinline__ float blo(unsigned u) { return __uint_as_float(u << 16); }
__device__ __forceinline__ float bhi(unsigned u) { return __uint_as_float(u & 0xffff0000u); }

// ---------------- coarse histogram: per-block counts -> gmat[bucket][block] ----------------
// gmat aliases the (not yet written) Hs region; fully overwritten, no memset needed.
__global__ __launch_bounds__(256) void k_hist(const int* __restrict__ dst,
                                              int* __restrict__ gmat) {
    __shared__ int h[NB];
    for (int i = threadIdx.x; i < NB; i += 256) h[i] = 0;
    __syncthreads();
    const int tid = blockIdx.x * 256 + threadIdx.x, nt = HB * 256;
    for (int e = tid; e < E; e += nt) atomicAdd(&h[dst[e] >> SHIFT], 1);
    __syncthreads();
    for (int i = threadIdx.x; i < NB; i += 256)
        gmat[i * HB + blockIdx.x] = h[i];
}

// ---------------- sum gmat rows + scan 196 bucket totals ----------------
__global__ void k_bscan(const int* __restrict__ gmat, int* __restrict__ base,
                        int* __restrict__ cursor) {
    __shared__ int sb[256];
    const int t = threadIdx.x;
    int v = 0;
    if (t < NB) {
        const int4* row = (const int4*)(gmat + t * HB);
        #pragma unroll 8
        for (int j = 0; j < HB / 4; ++j) {
            int4 a = row[j];
            v += (a.x + a.y) + (a.z + a.w);
        }
    }
    sb[t] = v; __syncthreads();
    for (int off = 1; off < 256; off <<= 1) {
        int x = (t >= off) ? sb[t - off] : 0;
        __syncthreads();
        sb[t] += x;
        __syncthreads();
    }
    if (t < NB) { int ex = sb[t] - v; base[t] = ex; cursor[t] = ex; }
    if (t == 0) base[NB] = E;
}

// ---------------- partition edges into coarse buckets ----------------
__global__ __launch_bounds__(256) void k_part(const int* __restrict__ src,
                                              const int* __restrict__ dst,
                                              int* __restrict__ cursor,
                                              unsigned* __restrict__ packed) {
    __shared__ int lh[NB], lb[NB], lc[NB];
    const int t = threadIdx.x;
    const int beg = blockIdx.x * CHUNK, end = beg + CHUNK;
    for (int i = t; i < NB; i += 256) lh[i] = 0;
    __syncthreads();
    for (int e = beg + t; e < end; e += 256) atomicAdd(&lh[dst[e] >> SHIFT], 1);
    __syncthreads();
    for (int i = t; i < NB; i += 256) {
        lb[i] = lh[i] ? atomicAdd(&cursor[i], lh[i]) : 0;
        lc[i] = 0;
    }
    __syncthreads();
    for (int e = beg + t; e < end; e += 256) {
        int d = dst[e], b = d >> SHIFT;
        int idx = atomicAdd(&lc[b], 1);
        packed[lb[b] + idx] = ((unsigned)(d & (NPB - 1)) << 17) | (unsigned)src[e];
    }
}

// ---------------- per-bucket CSR build: offs + dinv + in-place sorted csr ----------------
__global__ __launch_bounds__(512) void k_build(const int* __restrict__ bbase,
                                               unsigned* __restrict__ packed,
                                               int* __restrict__ offs,
                                               float* __restrict__ dinv) {
    __shared__ int cnt[NPB];
    __shared__ unsigned stage[CAP];            // 64 KB
    const int t = threadIdx.x, b = blockIdx.x;
    const int base = bbase[b], cntE = bbase[b + 1] - base;
    const int node0 = b << SHIFT;
    cnt[t] = 0;
    __syncthreads();
    for (int i = t; i < cntE; i += 512) atomicAdd(&cnt[packed[base + i] >> 17], 1);
    __syncthreads();
    const int v = cnt[t];
    __syncthreads();
    for (int off = 1; off < NPB; off <<= 1) {
        int x = (t >= off) ? cnt[t - off] : 0;
        __syncthreads();
        cnt[t] += x;
        __syncthreads();
    }
    const int ex = cnt[t] - v;
    const int node = node0 + t;
    if (node < N) {
        offs[node] = base + ex;
        dinv[node] = rsqrtf((float)v + 1.0f);  // +1 self loop
    }
    if (node == N) offs[N] = E;
    __syncthreads();
    cnt[t] = ex;
    __syncthreads();
    for (int i = t; i < cntE; i += 512) {
        unsigned p = packed[base + i];
        int idx = atomicAdd(&cnt[p >> 17], 1);
        if (idx < CAP) stage[idx] = p & 0x1FFFFu;
    }
    __syncthreads();
    for (int i = t; i < cntE; i += 512)
        packed[base + i] = stage[i];           // in-place: csr == packed buffer
}

// ---------------- GEMM1: Hs = bf16(dinv[row] * (X @ W1)) ----------------
// Inner loop k-by-4 with float4 xs reads: 6 LDS issues per 4k (was 12),
// identical FP accumulation order.
__global__ __launch_bounds__(256) void k_gemm1(const float* __restrict__ X,
                                               const float* __restrict__ W,
                                               const float* __restrict__ dinv,
                                               unsigned short* __restrict__ Hs) {
    constexpr int R  = 32;
    constexpr int XS = IN + 4;                 // 132; 132*4=528 ≡ 0 mod 16 (b128-aligned)
    __shared__ float ws[IN * HID];             // 32 KB
    __shared__ float xs[R * XS];
    const int t    = threadIdx.x;
    const int row0 = blockIdx.x * R;

    // zero-row (index N) for the padded gathers: written once, consumed by k_gather1f
    if (blockIdx.x == 0 && t < HID / 2)
        ((unsigned*)(Hs + (size_t)N * HID))[t] = 0u;

    for (int i = t; i < IN * HID / 4; i += 256)
        ((float4*)ws)[i] = ((const float4*)W)[i];
    for (int i = t; i < R * IN / 4; i += 256) {
        int r = i / (IN / 4), k4 = i % (IN / 4);
        *(float4*)&xs[r * XS + k4 * 4] =
            ((const float4*)(X + (size_t)(row0 + r) * IN))[k4];
    }
    __syncthreads();

    const int col0 = (t & 15) * 4;
    const int r0   = (t >> 4) * 2;
    float4 a0 = {0, 0, 0, 0}, a1 = {0, 0, 0, 0};
    for (int k = 0; k < IN; k += 4) {
        float4 x0v = *(const float4*)&xs[r0 * XS + k];
        float4 x1v = *(const float4*)&xs[(r0 + 1) * XS + k];
        float4 w0 = *(const float4*)&ws[(k + 0) * HID + col0];
        float4 w1 = *(const float4*)&ws[(k + 1) * HID + col0];
        float4 w2 = *(const float4*)&ws[(k + 2) * HID + col0];
        float4 w3 = *(const float4*)&ws[(k + 3) * HID + col0];
        a0.x += x0v.x * w0.x; a0.y += x0v.x * w0.y; a0.z += x0v.x * w0.z; a0.w += x0v.x * w0.w;
        a1.x += x1v.x * w0.x; a1.y += x1v.x * w0.y; a1.z += x1v.x * w0.z; a1.w += x1v.x * w0.w;
        a0.x += x0v.y * w1.x; a0.y += x0v.y * w1.y; a0.z += x0v.y * w1.z; a0.w += x0v.y * w1.w;
        a1.x += x1v.y * w1.x; a1.y += x1v.y * w1.y; a1.z += x1v.y * w1.z; a1.w += x1v.y * w1.w;
        a0.x += x0v.z * w2.x; a0.y += x0v.z * w2.y; a0.z += x0v.z * w2.z; a0.w += x0v.z * w2.w;
        a1.x += x1v.z * w2.x; a1.y += x1v.z * w2.y; a1.z += x1v.z * w2.z; a1.w += x1v.z * w2.w;
        a0.x += x0v.w * w3.x; a0.y += x0v.w * w3.y; a0.z += x0v.w * w3.z; a0.w += x0v.w * w3.w;
        a1.x += x1v.w * w3.x; a1.y += x1v.w * w3.y; a1.z += x1v.w * w3.z; a1.w += x1v.w * w3.w;
    }
    const float d0 = dinv[row0 + r0];
    const float d1 = dinv[row0 + r0 + 1];
    ushort4 p0 = {f2bf(a0.x * d0), f2bf(a0.y * d0), f2bf(a0.z * d0), f2bf(a0.w * d0)};
    ushort4 p1 = {f2bf(a1.x * d1), f2bf(a1.y * d1), f2bf(a1.z * d1), f2bf(a1.w * d1)};
    *(ushort4*)(Hs + (size_t)(row0 + r0) * HID + col0)       = p0;
    *(ushort4*)(Hs + (size_t)(row0 + r0 + 1) * HID + col0)   = p1;
}

// ---------------- gather1 + fused gemm2 ----------------
// Each HALF-WAVE owns one node. Neighbor lists padded to a multiple of 8 with
// index N (zeroed row) -> unconditional gather, 8 loads in flight.
// Launched as TWO half-grid dispatches (nodeBase param) so the true #2 kernel
// shows up in the rocprof top-5 window.
__global__ __launch_bounds__(256) void k_gather1f(const int* __restrict__ offs,
                                                  const int* __restrict__ csr,
                                                  const float* __restrict__ dinv,
                                                  const unsigned short* __restrict__ Hs,
                                                  const float* __restrict__ b1,
                                                  const float* __restrict__ W2,
                                                  unsigned* __restrict__ H2u,
                                                  int nodeBase) {
    __shared__ float w2s[HID * OUTC];          // 8 KB
    __shared__ int   sidx[4][2][96];           // 3 KB (deg max ~45, rdeg8 <= 52 << 96)
    __shared__ float wrow[4][2][64];           // 2 KB
    const int t = threadIdx.x;
    // zero-row (index N) of H2u for k_gather2's padded gather
    if (nodeBase == 0 && blockIdx.x == 0 && t < OUTC / 2) H2u[(size_t)N * 16 + t] = 0u;
    for (int i = t; i < HID * OUTC / 4; i += 256)
        ((float4*)w2s)[i] = ((const float4*)W2)[i];
    __syncthreads();

    const int wave = t >> 6, lane = t & 63, half = lane >> 5, c2 = lane & 31;
    const int nA = nodeBase + blockIdx.x * 8 + wave * 2;   // N % 16 == 0
    const int myNode = nA + half;
    const int o0 = offs[myNode], o1 = offs[myNode + 1];
    const int deg  = o1 - o0;
    const int rdeg = (deg + 7) & ~7;
    // stage this node's neighbor indices (same-wave: no barrier needed)
    for (int i = c2; i < deg; i += 32) sidx[wave][half][i] = csr[o0 + i];
    if (c2 < rdeg - deg) sidx[wave][half][deg + c2] = N;   // pad -> zero row

    const unsigned* __restrict__ Hu = (const unsigned*)Hs; // row stride 32 dwords
    const float dn = dinv[myNode];
    unsigned su = Hu[(size_t)myNode * 32 + c2];            // self loop (pre-scaled)
    float ax0 = blo(su), ay0 = bhi(su);
    float ax1 = 0, ay1 = 0, ax2 = 0, ay2 = 0, ax3 = 0, ay3 = 0;
    float ax4 = 0, ay4 = 0, ax5 = 0, ay5 = 0, ax6 = 0, ay6 = 0, ax7 = 0, ay7 = 0;
    for (int k = 0; k < rdeg; k += 8) {
        int4 sa = *(const int4*)&sidx[wave][half][k];      // ds_read_b128
        int4 sb = *(const int4*)&sidx[wave][half][k + 4];  // ds_read_b128
        unsigned u0 = Hu[(size_t)sa.x * 32 + c2];
        unsigned u1 = Hu[(size_t)sa.y * 32 + c2];
        unsigned u2 = Hu[(size_t)sa.z * 32 + c2];
        unsigned u3 = Hu[(size_t)sa.w * 32 + c2];
        unsigned u4 = Hu[(size_t)sb.x * 32 + c2];
        unsigned u5 = Hu[(size_t)sb.y * 32 + c2];
        unsigned u6 = Hu[(size_t)sb.z * 32 + c2];
        unsigned u7 = Hu[(size_t)sb.w * 32 + c2];
        ax0 += blo(u0);  ay0 += bhi(u0);
        ax1 += blo(u1);  ay1 += bhi(u1);
        ax2 += blo(u2);  ay2 += bhi(u2);
        ax3 += blo(u3);  ay3 += bhi(u3);
        ax4 += blo(u4);  ay4 += bhi(u4);
        ax5 += blo(u5);  ay5 += bhi(u5);
        ax6 += blo(u6);  ay6 += bhi(u6);
        ax7 += blo(u7);  ay7 += bhi(u7);
    }
    float sx = ((ax0 + ax1) + (ax2 + ax3)) + ((ax4 + ax5) + (ax6 + ax7));
    float sy = ((ay0 + ay1) + (ay2 + ay3)) + ((ay4 + ay5) + (ay6 + ay7));
    float2 bb = *(const float2*)(b1 + 2 * c2);
    wrow[wave][half][2 * c2]     = fmaxf(sx * dn + bb.x, 0.0f);   // fused relu+bias
    wrow[wave][half][2 * c2 + 1] = fmaxf(sy * dn + bb.y, 0.0f);

    // fused gemm2: each half dots ITS node's O1 row with W2 column c2
    float acc = 0.0f;
    #pragma unroll 16
    for (int k = 0; k < HID; ++k)
        acc += wrow[wave][half][k] * w2s[k * OUTC + c2];
    float hv = acc * dn;                                   // pre-scale by dinv
    float hv1 = __shfl_down(hv, 1, 64);
    if ((c2 & 1) == 0)
        H2u[(size_t)myNode * 16 + (c2 >> 1)] =
            (unsigned)f2bf(hv) | ((unsigned)f2bf(hv1) << 16);
}

// ---------------- gather2: each QUARTER-WAVE owns a node (4 nodes/wave) ----------------
// Same zero-row-padded unconditional gather, unroll-8.
__global__ __launch_bounds__(256) void k_gather2(const int* __restrict__ offs,
                                                 const int* __restrict__ csr,
                                                 const float* __restrict__ dinv,
                                                 const unsigned* __restrict__ H2u,
                                                 const float* __restrict__ b2,
                                                 float* __restrict__ out) {
    __shared__ int sidx[4][4][96];             // 6 KB
    const int t = threadIdx.x;
    const int wave = t >> 6, lane = t & 63, q = lane >> 4, c2 = lane & 15;
    const int n0 = blockIdx.x * 16 + wave * 4;             // N % 16 == 0
    const int myNode = n0 + q;
    const int o0 = offs[myNode], o1 = offs[myNode + 1];
    const int deg  = o1 - o0;
    const int rdeg = (deg + 7) & ~7;
    for (int i = c2; i < deg; i += 16) sidx[wave][q][i] = csr[o0 + i];
    if (c2 < rdeg - deg) sidx[wave][q][deg + c2] = N;      // pad -> zero row

    const float dn = dinv[myNode];
    unsigned su = H2u[(size_t)myNode * 16 + c2];           // self loop (pre-scaled)
    float ax0 = blo(su), ay0 = bhi(su);
    float ax1 = 0, ay1 = 0, ax2 = 0, ay2 = 0, ax3 = 0, ay3 = 0;
    float ax4 = 0, ay4 = 0, ax5 = 0, ay5 = 0, ax6 = 0, ay6 = 0, ax7 = 0, ay7 = 0;
    for (int k = 0; k < rdeg; k += 8) {
        int4 sa = *(const int4*)&sidx[wave][q][k];         // ds_read_b128
        int4 sb = *(const int4*)&sidx[wave][q][k + 4];     // ds_read_b128
        unsigned u0 = H2u[(size_t)sa.x * 16 + c2];
        unsigned u1 = H2u[(size_t)sa.y * 16 + c2];
        unsigned u2 = H2u[(size_t)sa.z * 16 + c2];
        unsigned u3 = H2u[(size_t)sa.w * 16 + c2];
        unsigned u4 = H2u[(size_t)sb.x * 16 + c2];
        unsigned u5 = H2u[(size_t)sb.y * 16 + c2];
        unsigned u6 = H2u[(size_t)sb.z * 16 + c2];
        unsigned u7 = H2u[(size_t)sb.w * 16 + c2];
        ax0 += blo(u0);  ay0 += bhi(u0);
        ax1 += blo(u1);  ay1 += bhi(u1);
        ax2 += blo(u2);  ay2 += bhi(u2);
        ax3 += blo(u3);  ay3 += bhi(u3);
        ax4 += blo(u4);  ay4 += bhi(u4);
        ax5 += blo(u5);  ay5 += bhi(u5);
        ax6 += blo(u6);  ay6 += bhi(u6);
        ax7 += blo(u7);  ay7 += bhi(u7);
    }
    float sx = ((ax0 + ax1) + (ax2 + ax3)) + ((ax4 + ax5) + (ax6 + ax7));
    float sy = ((ay0 + ay1) + (ay2 + ay3)) + ((ay4 + ay5) + (ay6 + ay7));
    float2 bb = *(const float2*)(b2 + 2 * c2);
    float2 r;
    r.x = sx * dn + bb.x;
    r.y = sy * dn + bb.y;
    *(float2*)(out + (size_t)myNode * OUTC + 2 * c2) = r;  // wave-coalesced 512B
}

extern "C" void kernel_launch(void* const* d_in, const int* in_sizes, int n_in,
                              void* d_out, int out_size, void* d_ws, size_t ws_size,
                              hipStream_t stream) {
    const float* x   = (const float*)d_in[0];
    const int*   ei  = (const int*)d_in[1];
    const float* W1  = (const float*)d_in[2];
    const float* b1  = (const float*)d_in[3];
    const float* W2  = (const float*)d_in[4];
    const float* b2  = (const float*)d_in[5];
    float*       out = (float*)d_out;

    const int* srcp = ei;
    const int* dstp = ei + E;

    char* ws = (char*)d_ws;
    int*            bbase  = (int*)(ws + 4096);                // 788 B
    int*            cursor = (int*)(ws + 8192);                // 784 B
    int*            offs   = (int*)(ws + 16384);               // 400,004 B
    float*          dinv   = (float*)(ws + (512u << 10));      // 400 KB
    unsigned*       packed = (unsigned*)(ws + (1u << 20));     // 6.4 MB (becomes csr in place)
    unsigned short* Hs     = (unsigned short*)(ws + (8u << 20));   // 12.8 MB + zero row
    unsigned*       H2u    = (unsigned*)(ws + (21u << 20));    // 6.4 MB + zero row
    int*            csr    = (int*)packed;
    int*            gmat   = (int*)Hs;   // NB*HB ints, dead before k_gemm1 writes Hs

    k_hist <<<HB, 256, 0, stream>>>(dstp, gmat);
    k_bscan<<<1, 256, 0, stream>>>(gmat, bbase, cursor);
    k_part <<<PB, 256, 0, stream>>>(srcp, dstp, cursor, packed);
    k_build<<<NB, 512, 0, stream>>>(bbase, packed, offs, dinv);

    k_gemm1   <<<N / 32, 256, 0, stream>>>(x, W1, dinv, Hs);
    k_gather1f<<<N / 16, 256, 0, stream>>>(offs, csr, dinv, Hs, b1, W2, H2u, 0);
    k_gather1f<<<N / 16, 256, 0, stream>>>(offs, csr, dinv, Hs, b1, W2, H2u, N / 2);
    k_gather2 <<<N / 16, 256, 0, stream>>>(offs, csr, dinv, H2u, b2, out);
}

// Round 5
// 232.284 us; speedup vs baseline: 1.0686x; 1.0686x over previous
//
#include <hip/hip_runtime.h>

constexpr int N  = 100000;
constexpr int E  = 1600000;
constexpr int IN = 128, HID = 64, OUTC = 32;

// coarse radix partition params (R6-proven)
constexpr int SHIFT = 9;                       // 512 nodes per bucket
constexpr int NPB   = 1 << SHIFT;              // 512
constexpr int NB    = (N + NPB - 1) / NPB;     // 196 buckets
constexpr int CAP   = 16384;                   // LDS stage cap (mean 8163, sigma~90)
constexpr int PB    = 800;                     // partition blocks (3 blocks/CU)
constexpr int CHUNK = E / PB;                  // 2000 (exact)
constexpr int HB    = 256;                     // hist blocks (gmat columns)

typedef __attribute__((ext_vector_type(8))) short bf16x8_t;  // 8 bf16 (4 VGPR)
typedef __attribute__((ext_vector_type(4))) float f32x4_t;   // 4 fp32

// ---- bf16 helpers ----
__device__ __forceinline__ unsigned short f2bf(float f) {
    union { float f; unsigned int u; } v; v.f = f;
    unsigned int u = v.u;
    return (unsigned short)((u + 0x7fffu + ((u >> 16) & 1u)) >> 16);
}
__device__ __forceinline__ float blo(unsigned u) { return __uint_as_float(u << 16); }
__device__ __forceinline__ float bhi(unsigned u) { return __uint_as_float(u & 0xffff0000u); }

// ---------------- coarse histogram: per-block counts -> gmat[bucket][block] ----------------
__global__ __launch_bounds__(256) void k_hist(const int* __restrict__ dst,
                                              int* __restrict__ gmat) {
    __shared__ int h[NB];
    for (int i = threadIdx.x; i < NB; i += 256) h[i] = 0;
    __syncthreads();
    const int tid = blockIdx.x * 256 + threadIdx.x, nt = HB * 256;
    for (int e = tid; e < E; e += nt) atomicAdd(&h[dst[e] >> SHIFT], 1);
    __syncthreads();
    for (int i = threadIdx.x; i < NB; i += 256)
        gmat[i * HB + blockIdx.x] = h[i];
}

// ---------------- sum gmat rows + scan 196 bucket totals ----------------
__global__ void k_bscan(const int* __restrict__ gmat, int* __restrict__ base,
                        int* __restrict__ cursor) {
    __shared__ int sb[256];
    const int t = threadIdx.x;
    int v = 0;
    if (t < NB) {
        const int4* row = (const int4*)(gmat + t * HB);
        #pragma unroll 8
        for (int j = 0; j < HB / 4; ++j) {
            int4 a = row[j];
            v += (a.x + a.y) + (a.z + a.w);
        }
    }
    sb[t] = v; __syncthreads();
    for (int off = 1; off < 256; off <<= 1) {
        int x = (t >= off) ? sb[t - off] : 0;
        __syncthreads();
        sb[t] += x;
        __syncthreads();
    }
    if (t < NB) { int ex = sb[t] - v; base[t] = ex; cursor[t] = ex; }
    if (t == 0) base[NB] = E;
}

// ---------------- partition edges into coarse buckets ----------------
__global__ __launch_bounds__(256) void k_part(const int* __restrict__ src,
                                              const int* __restrict__ dst,
                                              int* __restrict__ cursor,
                                              unsigned* __restrict__ packed) {
    __shared__ int lh[NB], lb[NB], lc[NB];
    const int t = threadIdx.x;
    const int beg = blockIdx.x * CHUNK, end = beg + CHUNK;
    for (int i = t; i < NB; i += 256) lh[i] = 0;
    __syncthreads();
    for (int e = beg + t; e < end; e += 256) atomicAdd(&lh[dst[e] >> SHIFT], 1);
    __syncthreads();
    for (int i = t; i < NB; i += 256) {
        lb[i] = lh[i] ? atomicAdd(&cursor[i], lh[i]) : 0;
        lc[i] = 0;
    }
    __syncthreads();
    for (int e = beg + t; e < end; e += 256) {
        int d = dst[e], b = d >> SHIFT;
        int idx = atomicAdd(&lc[b], 1);
        packed[lb[b] + idx] = ((unsigned)(d & (NPB - 1)) << 17) | (unsigned)src[e];
    }
}

// ---------------- per-bucket CSR build: offs + dinv + in-place sorted csr ----------------
__global__ __launch_bounds__(512) void k_build(const int* __restrict__ bbase,
                                               unsigned* __restrict__ packed,
                                               int* __restrict__ offs,
                                               float* __restrict__ dinv) {
    __shared__ int cnt[NPB];
    __shared__ unsigned stage[CAP];            // 64 KB
    const int t = threadIdx.x, b = blockIdx.x;
    const int base = bbase[b], cntE = bbase[b + 1] - base;
    const int node0 = b << SHIFT;
    cnt[t] = 0;
    __syncthreads();
    for (int i = t; i < cntE; i += 512) atomicAdd(&cnt[packed[base + i] >> 17], 1);
    __syncthreads();
    const int v = cnt[t];
    __syncthreads();
    for (int off = 1; off < NPB; off <<= 1) {
        int x = (t >= off) ? cnt[t - off] : 0;
        __syncthreads();
        cnt[t] += x;
        __syncthreads();
    }
    const int ex = cnt[t] - v;
    const int node = node0 + t;
    if (node < N) {
        offs[node] = base + ex;
        dinv[node] = rsqrtf((float)v + 1.0f);  // +1 self loop
    }
    if (node == N) offs[N] = E;
    __syncthreads();
    cnt[t] = ex;
    __syncthreads();
    for (int i = t; i < cntE; i += 512) {
        unsigned p = packed[base + i];
        int idx = atomicAdd(&cnt[p >> 17], 1);
        if (idx < CAP) stage[idx] = p & 0x1FFFFu;
    }
    __syncthreads();
    for (int i = t; i < cntE; i += 512)
        packed[base + i] = stage[i];           // in-place: csr == packed buffer
}

// ---------------- GEMM1 via split-bf16 MFMA: Hs = bf16(dinv[row] * (X @ W1)) ----------------
// x = xh + xl, w = wh + wl (bf16 each); X@W ~= xh wh + xl wh + xh wl, fp32 accum.
// Error ~2^-17 * |x||w|  <<  bf16 storage ulp of Hs -> absmax unchanged.
// 1 wave/block, 16 rows x 64 cols per wave, ZERO LDS. W fragments live in
// registers (128 VGPR, L1-hot scalar loads); their prep hides the A-tile
// HBM latency (A = 8 dwordx4 issued first).
// Fragment layouts (mfma_f32_16x16x32_bf16, m89-verified D):
//   A: lane l holds A[l&15][(l>>4)*8 + e]      (row-major tile of X)
//   B: lane l holds B[(l>>4)*8 + e][l&15]      (k-major column slice of W)
//   D: lane l, reg r -> D[(l>>4)*4 + r][l&15]
__global__ __launch_bounds__(64) void k_gemm1(const float* __restrict__ X,
                                              const float* __restrict__ W,
                                              const float* __restrict__ dinv,
                                              unsigned short* __restrict__ Hs) {
    const int l    = threadIdx.x;
    const int row0 = blockIdx.x * 16;
    const int rlo  = l & 15, khi = l >> 4;     // khi in 0..3

    // zero-row (index N) for the padded gathers
    if (blockIdx.x == 0 && l < HID / 2)
        ((unsigned*)(Hs + (size_t)N * HID))[l] = 0u;

    // --- issue A-tile loads early (HBM latency hides under W-prep) ---
    const float* xrow = X + (size_t)(row0 + rlo) * IN + khi * 8;
    float4 xa[4], xb[4];
    #pragma unroll
    for (int ks = 0; ks < 4; ++ks) {
        xa[ks] = *(const float4*)(xrow + ks * 32);
        xb[ks] = *(const float4*)(xrow + ks * 32 + 4);
    }

    // --- W fragments, split hi/lo: 4 k-steps x 4 col-tiles ---
    bf16x8_t wh[4][4], wl[4][4];
    #pragma unroll
    for (int ks = 0; ks < 4; ++ks) {
        #pragma unroll
        for (int ct = 0; ct < 4; ++ct) {
            const float* wp = W + (ks * 32 + khi * 8) * HID + ct * 16 + rlo;
            #pragma unroll
            for (int e = 0; e < 8; ++e) {
                float w = wp[e * HID];
                unsigned short h = f2bf(w);
                float r = w - __uint_as_float((unsigned)h << 16);
                wh[ks][ct][e] = (short)h;
                wl[ks][ct][e] = (short)f2bf(r);
            }
        }
    }

    f32x4_t acc[4] = {{0,0,0,0},{0,0,0,0},{0,0,0,0},{0,0,0,0}};
    #pragma unroll
    for (int ks = 0; ks < 4; ++ks) {
        float xr[8] = {xa[ks].x, xa[ks].y, xa[ks].z, xa[ks].w,
                       xb[ks].x, xb[ks].y, xb[ks].z, xb[ks].w};
        bf16x8_t ah, al;
        #pragma unroll
        for (int e = 0; e < 8; ++e) {
            unsigned short h = f2bf(xr[e]);
            ah[e] = (short)h;
            al[e] = (short)f2bf(xr[e] - __uint_as_float((unsigned)h << 16));
        }
        // 12 MFMA, ct-interleaved so each acc chain has a 4-MFMA gap
        #pragma unroll
        for (int ct = 0; ct < 4; ++ct)
            acc[ct] = __builtin_amdgcn_mfma_f32_16x16x32_bf16(ah, wh[ks][ct], acc[ct], 0, 0, 0);
        #pragma unroll
        for (int ct = 0; ct < 4; ++ct)
            acc[ct] = __builtin_amdgcn_mfma_f32_16x16x32_bf16(al, wh[ks][ct], acc[ct], 0, 0, 0);
        #pragma unroll
        for (int ct = 0; ct < 4; ++ct)
            acc[ct] = __builtin_amdgcn_mfma_f32_16x16x32_bf16(ah, wl[ks][ct], acc[ct], 0, 0, 0);
    }

    // --- epilogue: scale by dinv, pack bf16, store ---
    const int orow = row0 + khi * 4;
    #pragma unroll
    for (int r = 0; r < 4; ++r) {
        const float d = dinv[orow + r];
        #pragma unroll
        for (int ct = 0; ct < 4; ++ct)
            Hs[(size_t)(orow + r) * HID + ct * 16 + rlo] = f2bf(acc[ct][r] * d);
    }
}

// ---------------- gather1 + fused gemm2 ----------------
// Each HALF-WAVE owns one node. Neighbor lists padded to a multiple of 8 with
// index N (zeroed row) -> unconditional gather, 8 loads in flight.
__global__ __launch_bounds__(256) void k_gather1f(const int* __restrict__ offs,
                                                  const int* __restrict__ csr,
                                                  const float* __restrict__ dinv,
                                                  const unsigned short* __restrict__ Hs,
                                                  const float* __restrict__ b1,
                                                  const float* __restrict__ W2,
                                                  unsigned* __restrict__ H2u) {
    __shared__ float w2s[HID * OUTC];          // 8 KB
    __shared__ int   sidx[4][2][96];           // 3 KB (deg max ~45, rdeg8 <= 52 << 96)
    __shared__ float wrow[4][2][64];           // 2 KB
    const int t = threadIdx.x;
    // zero-row (index N) of H2u for k_gather2's padded gather
    if (blockIdx.x == 0 && t < OUTC / 2) H2u[(size_t)N * 16 + t] = 0u;
    for (int i = t; i < HID * OUTC / 4; i += 256)
        ((float4*)w2s)[i] = ((const float4*)W2)[i];
    __syncthreads();

    const int wave = t >> 6, lane = t & 63, half = lane >> 5, c2 = lane & 31;
    const int nA = blockIdx.x * 8 + wave * 2;              // N % 8 == 0
    const int myNode = nA + half;
    const int o0 = offs[myNode], o1 = offs[myNode + 1];
    const int deg  = o1 - o0;
    const int rdeg = (deg + 7) & ~7;
    // stage this node's neighbor indices (same-wave: no barrier needed)
    for (int i = c2; i < deg; i += 32) sidx[wave][half][i] = csr[o0 + i];
    if (c2 < rdeg - deg) sidx[wave][half][deg + c2] = N;   // pad -> zero row

    const unsigned* __restrict__ Hu = (const unsigned*)Hs; // row stride 32 dwords
    const float dn = dinv[myNode];
    unsigned su = Hu[(size_t)myNode * 32 + c2];            // self loop (pre-scaled)
    float ax0 = blo(su), ay0 = bhi(su);
    float ax1 = 0, ay1 = 0, ax2 = 0, ay2 = 0, ax3 = 0, ay3 = 0;
    float ax4 = 0, ay4 = 0, ax5 = 0, ay5 = 0, ax6 = 0, ay6 = 0, ax7 = 0, ay7 = 0;
    for (int k = 0; k < rdeg; k += 8) {
        int4 sa = *(const int4*)&sidx[wave][half][k];      // ds_read_b128
        int4 sb = *(const int4*)&sidx[wave][half][k + 4];  // ds_read_b128
        unsigned u0 = Hu[(size_t)sa.x * 32 + c2];
        unsigned u1 = Hu[(size_t)sa.y * 32 + c2];
        unsigned u2 = Hu[(size_t)sa.z * 32 + c2];
        unsigned u3 = Hu[(size_t)sa.w * 32 + c2];
        unsigned u4 = Hu[(size_t)sb.x * 32 + c2];
        unsigned u5 = Hu[(size_t)sb.y * 32 + c2];
        unsigned u6 = Hu[(size_t)sb.z * 32 + c2];
        unsigned u7 = Hu[(size_t)sb.w * 32 + c2];
        ax0 += blo(u0);  ay0 += bhi(u0);
        ax1 += blo(u1);  ay1 += bhi(u1);
        ax2 += blo(u2);  ay2 += bhi(u2);
        ax3 += blo(u3);  ay3 += bhi(u3);
        ax4 += blo(u4);  ay4 += bhi(u4);
        ax5 += blo(u5);  ay5 += bhi(u5);
        ax6 += blo(u6);  ay6 += bhi(u6);
        ax7 += blo(u7);  ay7 += bhi(u7);
    }
    float sx = ((ax0 + ax1) + (ax2 + ax3)) + ((ax4 + ax5) + (ax6 + ax7));
    float sy = ((ay0 + ay1) + (ay2 + ay3)) + ((ay4 + ay5) + (ay6 + ay7));
    float2 bb = *(const float2*)(b1 + 2 * c2);
    wrow[wave][half][2 * c2]     = fmaxf(sx * dn + bb.x, 0.0f);   // fused relu+bias
    wrow[wave][half][2 * c2 + 1] = fmaxf(sy * dn + bb.y, 0.0f);

    // fused gemm2: each half dots ITS node's O1 row with W2 column c2
    float acc = 0.0f;
    #pragma unroll 16
    for (int k = 0; k < HID; ++k)
        acc += wrow[wave][half][k] * w2s[k * OUTC + c2];
    float hv = acc * dn;                                   // pre-scale by dinv
    float hv1 = __shfl_down(hv, 1, 64);
    if ((c2 & 1) == 0)
        H2u[(size_t)myNode * 16 + (c2 >> 1)] =
            (unsigned)f2bf(hv) | ((unsigned)f2bf(hv1) << 16);
}

// ---------------- gather2: each QUARTER-WAVE owns a node (4 nodes/wave) ----------------
// Same zero-row-padded unconditional gather, unroll-8.
__global__ __launch_bounds__(256) void k_gather2(const int* __restrict__ offs,
                                                 const int* __restrict__ csr,
                                                 const float* __restrict__ dinv,
                                                 const unsigned* __restrict__ H2u,
                                                 const float* __restrict__ b2,
                                                 float* __restrict__ out) {
    __shared__ int sidx[4][4][96];             // 6 KB
    const int t = threadIdx.x;
    const int wave = t >> 6, lane = t & 63, q = lane >> 4, c2 = lane & 15;
    const int n0 = blockIdx.x * 16 + wave * 4;             // N % 16 == 0
    const int myNode = n0 + q;
    const int o0 = offs[myNode], o1 = offs[myNode + 1];
    const int deg  = o1 - o0;
    const int rdeg = (deg + 7) & ~7;
    for (int i = c2; i < deg; i += 16) sidx[wave][q][i] = csr[o0 + i];
    if (c2 < rdeg - deg) sidx[wave][q][deg + c2] = N;      // pad -> zero row

    const float dn = dinv[myNode];
    unsigned su = H2u[(size_t)myNode * 16 + c2];           // self loop (pre-scaled)
    float ax0 = blo(su), ay0 = bhi(su);
    float ax1 = 0, ay1 = 0, ax2 = 0, ay2 = 0, ax3 = 0, ay3 = 0;
    float ax4 = 0, ay4 = 0, ax5 = 0, ay5 = 0, ax6 = 0, ay6 = 0, ax7 = 0, ay7 = 0;
    for (int k = 0; k < rdeg; k += 8) {
        int4 sa = *(const int4*)&sidx[wave][q][k];         // ds_read_b128
        int4 sb = *(const int4*)&sidx[wave][q][k + 4];     // ds_read_b128
        unsigned u0 = H2u[(size_t)sa.x * 16 + c2];
        unsigned u1 = H2u[(size_t)sa.y * 16 + c2];
        unsigned u2 = H2u[(size_t)sa.z * 16 + c2];
        unsigned u3 = H2u[(size_t)sa.w * 16 + c2];
        unsigned u4 = H2u[(size_t)sb.x * 16 + c2];
        unsigned u5 = H2u[(size_t)sb.y * 16 + c2];
        unsigned u6 = H2u[(size_t)sb.z * 16 + c2];
        unsigned u7 = H2u[(size_t)sb.w * 16 + c2];
        ax0 += blo(u0);  ay0 += bhi(u0);
        ax1 += blo(u1);  ay1 += bhi(u1);
        ax2 += blo(u2);  ay2 += bhi(u2);
        ax3 += blo(u3);  ay3 += bhi(u3);
        ax4 += blo(u4);  ay4 += bhi(u4);
        ax5 += blo(u5);  ay5 += bhi(u5);
        ax6 += blo(u6);  ay6 += bhi(u6);
        ax7 += blo(u7);  ay7 += bhi(u7);
    }
    float sx = ((ax0 + ax1) + (ax2 + ax3)) + ((ax4 + ax5) + (ax6 + ax7));
    float sy = ((ay0 + ay1) + (ay2 + ay3)) + ((ay4 + ay5) + (ay6 + ay7));
    float2 bb = *(const float2*)(b2 + 2 * c2);
    float2 r;
    r.x = sx * dn + bb.x;
    r.y = sy * dn + bb.y;
    *(float2*)(out + (size_t)myNode * OUTC + 2 * c2) = r;  // wave-coalesced 512B
}

extern "C" void kernel_launch(void* const* d_in, const int* in_sizes, int n_in,
                              void* d_out, int out_size, void* d_ws, size_t ws_size,
                              hipStream_t stream) {
    const float* x   = (const float*)d_in[0];
    const int*   ei  = (const int*)d_in[1];
    const float* W1  = (const float*)d_in[2];
    const float* b1  = (const float*)d_in[3];
    const float* W2  = (const float*)d_in[4];
    const float* b2  = (const float*)d_in[5];
    float*       out = (float*)d_out;

    const int* srcp = ei;
    const int* dstp = ei + E;

    char* ws = (char*)d_ws;
    int*            bbase  = (int*)(ws + 4096);                // 788 B
    int*            cursor = (int*)(ws + 8192);                // 784 B
    int*            offs   = (int*)(ws + 16384);               // 400,004 B
    float*          dinv   = (float*)(ws + (512u << 10));      // 400 KB
    unsigned*       packed = (unsigned*)(ws + (1u << 20));     // 6.4 MB (becomes csr in place)
    unsigned short* Hs     = (unsigned short*)(ws + (8u << 20));   // 12.8 MB + zero row
    unsigned*       H2u    = (unsigned*)(ws + (21u << 20));    // 6.4 MB + zero row
    int*            csr    = (int*)packed;
    int*            gmat   = (int*)Hs;   // NB*HB ints, dead before k_gemm1 writes Hs

    k_hist <<<HB, 256, 0, stream>>>(dstp, gmat);
    k_bscan<<<1, 256, 0, stream>>>(gmat, bbase, cursor);
    k_part <<<PB, 256, 0, stream>>>(srcp, dstp, cursor, packed);
    k_build<<<NB, 512, 0, stream>>>(bbase, packed, offs, dinv);

    k_gemm1   <<<N / 16, 64,  0, stream>>>(x, W1, dinv, Hs);
    k_gather1f<<<N / 8,  256, 0, stream>>>(offs, csr, dinv, Hs, b1, W2, H2u);
    k_gather2 <<<N / 16, 256, 0, stream>>>(offs, csr, dinv, H2u, b2, out);
}

// Round 6
// 225.074 us; speedup vs baseline: 1.1028x; 1.0320x over previous
//
#include <hip/hip_runtime.h>

constexpr int N  = 100000;
constexpr int E  = 1600000;
constexpr int IN = 128, HID = 64, OUTC = 32;

// coarse radix partition params (R6-proven)
constexpr int SHIFT = 9;                       // 512 nodes per bucket
constexpr int NPB   = 1 << SHIFT;              // 512
constexpr int NB    = (N + NPB - 1) / NPB;     // 196 buckets
constexpr int CAP   = 16384;                   // LDS stage cap (mean 8163, sigma~90)
constexpr int PB    = 800;                     // partition blocks (3 blocks/CU)
constexpr int CHUNK = E / PB;                  // 2000 (exact)
constexpr int HB    = 256;                     // hist blocks (gmat columns)
constexpr int G1T   = 5;                       // gemm1 tiles/block (80 rows)

typedef __attribute__((ext_vector_type(8))) short bf16x8_t;  // 8 bf16 (4 VGPR)
typedef __attribute__((ext_vector_type(4))) float f32x4_t;   // 4 fp32

// ---- bf16 helpers ----
__device__ __forceinline__ unsigned short f2bf(float f) {
    union { float f; unsigned int u; } v; v.f = f;
    unsigned int u = v.u;
    return (unsigned short)((u + 0x7fffu + ((u >> 16) & 1u)) >> 16);
}
__device__ __forceinline__ float blo(unsigned u) { return __uint_as_float(u << 16); }
__device__ __forceinline__ float bhi(unsigned u) { return __uint_as_float(u & 0xffff0000u); }

// ---------------- coarse histogram: per-block counts -> gmat[bucket][block] ----------------
__global__ __launch_bounds__(256) void k_hist(const int* __restrict__ dst,
                                              int* __restrict__ gmat) {
    __shared__ int h[NB];
    for (int i = threadIdx.x; i < NB; i += 256) h[i] = 0;
    __syncthreads();
    const int tid = blockIdx.x * 256 + threadIdx.x, nt = HB * 256;
    for (int e = tid; e < E; e += nt) atomicAdd(&h[dst[e] >> SHIFT], 1);
    __syncthreads();
    for (int i = threadIdx.x; i < NB; i += 256)
        gmat[i * HB + blockIdx.x] = h[i];
}

// ---------------- sum gmat rows + scan 196 bucket totals ----------------
__global__ void k_bscan(const int* __restrict__ gmat, int* __restrict__ base,
                        int* __restrict__ cursor) {
    __shared__ int sb[256];
    const int t = threadIdx.x;
    int v = 0;
    if (t < NB) {
        const int4* row = (const int4*)(gmat + t * HB);
        #pragma unroll 8
        for (int j = 0; j < HB / 4; ++j) {
            int4 a = row[j];
            v += (a.x + a.y) + (a.z + a.w);
        }
    }
    sb[t] = v; __syncthreads();
    for (int off = 1; off < 256; off <<= 1) {
        int x = (t >= off) ? sb[t - off] : 0;
        __syncthreads();
        sb[t] += x;
        __syncthreads();
    }
    if (t < NB) { int ex = sb[t] - v; base[t] = ex; cursor[t] = ex; }
    if (t == 0) base[NB] = E;
}

// ---------------- partition edges into coarse buckets ----------------
__global__ __launch_bounds__(256) void k_part(const int* __restrict__ src,
                                              const int* __restrict__ dst,
                                              int* __restrict__ cursor,
                                              unsigned* __restrict__ packed) {
    __shared__ int lh[NB], lb[NB], lc[NB];
    const int t = threadIdx.x;
    const int beg = blockIdx.x * CHUNK, end = beg + CHUNK;
    for (int i = t; i < NB; i += 256) lh[i] = 0;
    __syncthreads();
    for (int e = beg + t; e < end; e += 256) atomicAdd(&lh[dst[e] >> SHIFT], 1);
    __syncthreads();
    for (int i = t; i < NB; i += 256) {
        lb[i] = lh[i] ? atomicAdd(&cursor[i], lh[i]) : 0;
        lc[i] = 0;
    }
    __syncthreads();
    for (int e = beg + t; e < end; e += 256) {
        int d = dst[e], b = d >> SHIFT;
        int idx = atomicAdd(&lc[b], 1);
        packed[lb[b] + idx] = ((unsigned)(d & (NPB - 1)) << 17) | (unsigned)src[e];
    }
}

// ---------------- per-bucket CSR build: offs + dinv + in-place sorted csr ----------------
__global__ __launch_bounds__(512) void k_build(const int* __restrict__ bbase,
                                               unsigned* __restrict__ packed,
                                               int* __restrict__ offs,
                                               float* __restrict__ dinv) {
    __shared__ int cnt[NPB];
    __shared__ unsigned stage[CAP];            // 64 KB
    const int t = threadIdx.x, b = blockIdx.x;
    const int base = bbase[b], cntE = bbase[b + 1] - base;
    const int node0 = b << SHIFT;
    cnt[t] = 0;
    __syncthreads();
    for (int i = t; i < cntE; i += 512) atomicAdd(&cnt[packed[base + i] >> 17], 1);
    __syncthreads();
    const int v = cnt[t];
    __syncthreads();
    for (int off = 1; off < NPB; off <<= 1) {
        int x = (t >= off) ? cnt[t - off] : 0;
        __syncthreads();
        cnt[t] += x;
        __syncthreads();
    }
    const int ex = cnt[t] - v;
    const int node = node0 + t;
    if (node < N) {
        offs[node] = base + ex;
        dinv[node] = rsqrtf((float)v + 1.0f);  // +1 self loop
    }
    if (node == N) offs[N] = E;
    __syncthreads();
    cnt[t] = ex;
    __syncthreads();
    for (int i = t; i < cntE; i += 512) {
        unsigned p = packed[base + i];
        int idx = atomicAdd(&cnt[p >> 17], 1);
        if (idx < CAP) stage[idx] = p & 0x1FFFFu;
    }
    __syncthreads();
    for (int i = t; i < cntE; i += 512)
        packed[base + i] = stage[i];           // in-place: csr == packed buffer
}

// ---------------- GEMM1 via split-bf16 MFMA: Hs = bf16(dinv[row] * (X @ W1)) ----------------
// Same proven math as R5 (x=xh+xl, w=wh+wl; xh wh + xl wh + xh wl; fp32 acc).
// Now 5 tiles of 16 rows per block: W-fragment prep amortized 5x; next-tile
// A loads prefetched before the MFMA burst.
__global__ __launch_bounds__(64) void k_gemm1(const float* __restrict__ X,
                                              const float* __restrict__ W,
                                              const float* __restrict__ dinv,
                                              unsigned short* __restrict__ Hs) {
    const int l    = threadIdx.x;
    const int rlo  = l & 15, khi = l >> 4;     // khi in 0..3
    const int base = blockIdx.x * (16 * G1T);

    // zero-row (index N) for the padded gathers
    if (blockIdx.x == 0 && l < HID / 2)
        ((unsigned*)(Hs + (size_t)N * HID))[l] = 0u;

    // --- prefetch tile 0 A (HBM latency hides under W-prep) ---
    float4 xa[4], xb[4];
    {
        const float* xr = X + (size_t)(base + rlo) * IN + khi * 8;
        #pragma unroll
        for (int ks = 0; ks < 4; ++ks) {
            xa[ks] = *(const float4*)(xr + ks * 32);
            xb[ks] = *(const float4*)(xr + ks * 32 + 4);
        }
    }

    // --- W fragments, split hi/lo: 4 k-steps x 4 col-tiles (once per block) ---
    bf16x8_t wh[4][4], wl[4][4];
    #pragma unroll
    for (int ks = 0; ks < 4; ++ks) {
        #pragma unroll
        for (int ct = 0; ct < 4; ++ct) {
            const float* wp = W + (ks * 32 + khi * 8) * HID + ct * 16 + rlo;
            #pragma unroll
            for (int e = 0; e < 8; ++e) {
                float w = wp[e * HID];
                unsigned short h = f2bf(w);
                float r = w - __uint_as_float((unsigned)h << 16);
                wh[ks][ct][e] = (short)h;
                wl[ks][ct][e] = (short)f2bf(r);
            }
        }
    }

    #pragma unroll
    for (int tile = 0; tile < G1T; ++tile) {
        const int row0 = base + tile * 16;
        float4 cxa[4], cxb[4];
        #pragma unroll
        for (int ks = 0; ks < 4; ++ks) { cxa[ks] = xa[ks]; cxb[ks] = xb[ks]; }
        if (tile + 1 < G1T) {                  // prefetch next tile
            const float* xr = X + (size_t)(row0 + 16 + rlo) * IN + khi * 8;
            #pragma unroll
            for (int ks = 0; ks < 4; ++ks) {
                xa[ks] = *(const float4*)(xr + ks * 32);
                xb[ks] = *(const float4*)(xr + ks * 32 + 4);
            }
        }

        f32x4_t acc[4] = {{0,0,0,0},{0,0,0,0},{0,0,0,0},{0,0,0,0}};
        #pragma unroll
        for (int ks = 0; ks < 4; ++ks) {
            float xr8[8] = {cxa[ks].x, cxa[ks].y, cxa[ks].z, cxa[ks].w,
                            cxb[ks].x, cxb[ks].y, cxb[ks].z, cxb[ks].w};
            bf16x8_t ah, al;
            #pragma unroll
            for (int e = 0; e < 8; ++e) {
                unsigned short h = f2bf(xr8[e]);
                ah[e] = (short)h;
                al[e] = (short)f2bf(xr8[e] - __uint_as_float((unsigned)h << 16));
            }
            #pragma unroll
            for (int ct = 0; ct < 4; ++ct)
                acc[ct] = __builtin_amdgcn_mfma_f32_16x16x32_bf16(ah, wh[ks][ct], acc[ct], 0, 0, 0);
            #pragma unroll
            for (int ct = 0; ct < 4; ++ct)
                acc[ct] = __builtin_amdgcn_mfma_f32_16x16x32_bf16(al, wh[ks][ct], acc[ct], 0, 0, 0);
            #pragma unroll
            for (int ct = 0; ct < 4; ++ct)
                acc[ct] = __builtin_amdgcn_mfma_f32_16x16x32_bf16(ah, wl[ks][ct], acc[ct], 0, 0, 0);
        }

        const int orow = row0 + khi * 4;
        #pragma unroll
        for (int r = 0; r < 4; ++r) {
            const float d = dinv[orow + r];
            #pragma unroll
            for (int ct = 0; ct < 4; ++ct)
                Hs[(size_t)(orow + r) * HID + ct * 16 + rlo] = f2bf(acc[ct][r] * d);
        }
    }
}

// ---------------- gather1 + fused gemm2 ----------------
// QUARTER-WAVE per node, uint2 (8B) lanes: 16 lanes cover the 128B row,
// 4 nodes/wave, 8 rows in flight each -> 32 rows in flight per wave (2x R5).
// Zero-row padding (index N) keeps the loop predication-free.
__global__ __launch_bounds__(256) void k_gather1f(const int* __restrict__ offs,
                                                  const int* __restrict__ csr,
                                                  const float* __restrict__ dinv,
                                                  const unsigned short* __restrict__ Hs,
                                                  const float* __restrict__ b1,
                                                  const float* __restrict__ W2,
                                                  unsigned* __restrict__ H2u) {
    __shared__ float w2s[HID * OUTC];          // 8 KB
    __shared__ int   sidx[4][4][96];           // 6 KB
    __shared__ float wrow[4][4][64];           // 4 KB
    const int t = threadIdx.x;
    // zero-row (index N) of H2u for k_gather2's padded gather
    if (blockIdx.x == 0 && t < OUTC / 2) H2u[(size_t)N * 16 + t] = 0u;
    for (int i = t; i < HID * OUTC / 4; i += 256)
        ((float4*)w2s)[i] = ((const float4*)W2)[i];
    __syncthreads();

    const int wave = t >> 6, lane = t & 63, q = lane >> 4, c = lane & 15;
    const int myNode = blockIdx.x * 16 + wave * 4 + q;     // N % 16 == 0
    const int o0 = offs[myNode], o1 = offs[myNode + 1];
    const int deg  = o1 - o0;
    const int rdeg = (deg + 7) & ~7;
    for (int i = c; i < deg; i += 16) sidx[wave][q][i] = csr[o0 + i];
    if (c < rdeg - deg) sidx[wave][q][deg + c] = N;        // pad -> zero row

    const uint2* __restrict__ Hu2 = (const uint2*)Hs;      // row = 16 uint2
    const float dn = dinv[myNode];
    uint2 su = Hu2[(size_t)myNode * 16 + c];               // self loop (pre-scaled)
    float p0 = blo(su.x), p1 = bhi(su.x), p2 = blo(su.y), p3 = bhi(su.y);
    float r0 = 0, r1 = 0, r2 = 0, r3 = 0;
    for (int k = 0; k < rdeg; k += 8) {
        int4 sa = *(const int4*)&sidx[wave][q][k];         // ds_read_b128
        int4 sb = *(const int4*)&sidx[wave][q][k + 4];     // ds_read_b128
        uint2 u0 = Hu2[(size_t)sa.x * 16 + c];
        uint2 u1 = Hu2[(size_t)sa.y * 16 + c];
        uint2 u2 = Hu2[(size_t)sa.z * 16 + c];
        uint2 u3 = Hu2[(size_t)sa.w * 16 + c];
        uint2 u4 = Hu2[(size_t)sb.x * 16 + c];
        uint2 u5 = Hu2[(size_t)sb.y * 16 + c];
        uint2 u6 = Hu2[(size_t)sb.z * 16 + c];
        uint2 u7 = Hu2[(size_t)sb.w * 16 + c];
        p0 += blo(u0.x); p1 += bhi(u0.x); p2 += blo(u0.y); p3 += bhi(u0.y);
        r0 += blo(u1.x); r1 += bhi(u1.x); r2 += blo(u1.y); r3 += bhi(u1.y);
        p0 += blo(u2.x); p1 += bhi(u2.x); p2 += blo(u2.y); p3 += bhi(u2.y);
        r0 += blo(u3.x); r1 += bhi(u3.x); r2 += blo(u3.y); r3 += bhi(u3.y);
        p0 += blo(u4.x); p1 += bhi(u4.x); p2 += blo(u4.y); p3 += bhi(u4.y);
        r0 += blo(u5.x); r1 += bhi(u5.x); r2 += blo(u5.y); r3 += bhi(u5.y);
        p0 += blo(u6.x); p1 += bhi(u6.x); p2 += blo(u6.y); p3 += bhi(u6.y);
        r0 += blo(u7.x); r1 += bhi(u7.x); r2 += blo(u7.y); r3 += bhi(u7.y);
    }
    float s0 = p0 + r0, s1 = p1 + r1, s2 = p2 + r2, s3 = p3 + r3;
    float4 bb = *(const float4*)(b1 + 4 * c);
    float4 wv;
    wv.x = fmaxf(s0 * dn + bb.x, 0.0f);                    // fused relu+bias
    wv.y = fmaxf(s1 * dn + bb.y, 0.0f);
    wv.z = fmaxf(s2 * dn + bb.z, 0.0f);
    wv.w = fmaxf(s3 * dn + bb.w, 0.0f);
    *(float4*)&wrow[wave][q][4 * c] = wv;

    // fused gemm2: lane c computes outputs 2c, 2c+1 of ITS node (no shuffle)
    float acc0 = 0.0f, acc1 = 0.0f;
    #pragma unroll
    for (int k = 0; k < HID; k += 4) {
        float4 wr = *(const float4*)&wrow[wave][q][k];
        float2 wa = *(const float2*)&w2s[(k + 0) * OUTC + 2 * c];
        float2 wb = *(const float2*)&w2s[(k + 1) * OUTC + 2 * c];
        float2 wc = *(const float2*)&w2s[(k + 2) * OUTC + 2 * c];
        float2 wd = *(const float2*)&w2s[(k + 3) * OUTC + 2 * c];
        acc0 += wr.x * wa.x + wr.y * wb.x + wr.z * wc.x + wr.w * wd.x;
        acc1 += wr.x * wa.y + wr.y * wb.y + wr.z * wc.y + wr.w * wd.y;
    }
    H2u[(size_t)myNode * 16 + c] =
        (unsigned)f2bf(acc0 * dn) | ((unsigned)f2bf(acc1 * dn) << 16);
}

// ---------------- gather2: EIGHTH-WAVE per node, uint2 lanes ----------------
// 8 lanes cover the 64B row, 8 nodes/wave, 8 rows in flight each
// -> 64 rows in flight per wave (4x R5). float4 output store.
__global__ __launch_bounds__(256) void k_gather2(const int* __restrict__ offs,
                                                 const int* __restrict__ csr,
                                                 const float* __restrict__ dinv,
                                                 const unsigned* __restrict__ H2u,
                                                 const float* __restrict__ b2,
                                                 float* __restrict__ out) {
    __shared__ int sidx[4][8][96];             // 12 KB
    const int t = threadIdx.x;
    const int wave = t >> 6, lane = t & 63, q = lane >> 3, c = lane & 7;
    const int myNode = blockIdx.x * 32 + wave * 8 + q;     // N % 32 == 0
    const int o0 = offs[myNode], o1 = offs[myNode + 1];
    const int deg  = o1 - o0;
    const int rdeg = (deg + 7) & ~7;
    for (int i = c; i < deg; i += 8) sidx[wave][q][i] = csr[o0 + i];
    if (c < rdeg - deg) sidx[wave][q][deg + c] = N;        // pad -> zero row

    const uint2* __restrict__ H2 = (const uint2*)H2u;      // row = 8 uint2
    const float dn = dinv[myNode];
    uint2 su = H2[(size_t)myNode * 8 + c];                 // self loop (pre-scaled)
    float p0 = blo(su.x), p1 = bhi(su.x), p2 = blo(su.y), p3 = bhi(su.y);
    float r0 = 0, r1 = 0, r2 = 0, r3 = 0;
    for (int k = 0; k < rdeg; k += 8) {
        int4 sa = *(const int4*)&sidx[wave][q][k];         // ds_read_b128
        int4 sb = *(const int4*)&sidx[wave][q][k + 4];     // ds_read_b128
        uint2 u0 = H2[(size_t)sa.x * 8 + c];
        uint2 u1 = H2[(size_t)sa.y * 8 + c];
        uint2 u2 = H2[(size_t)sa.z * 8 + c];
        uint2 u3 = H2[(size_t)sa.w * 8 + c];
        uint2 u4 = H2[(size_t)sb.x * 8 + c];
        uint2 u5 = H2[(size_t)sb.y * 8 + c];
        uint2 u6 = H2[(size_t)sb.z * 8 + c];
        uint2 u7 = H2[(size_t)sb.w * 8 + c];
        p0 += blo(u0.x); p1 += bhi(u0.x); p2 += blo(u0.y); p3 += bhi(u0.y);
        r0 += blo(u1.x); r1 += bhi(u1.x); r2 += blo(u1.y); r3 += bhi(u1.y);
        p0 += blo(u2.x); p1 += bhi(u2.x); p2 += blo(u2.y); p3 += bhi(u2.y);
        r0 += blo(u3.x); r1 += bhi(u3.x); r2 += blo(u3.y); r3 += bhi(u3.y);
        p0 += blo(u4.x); p1 += bhi(u4.x); p2 += blo(u4.y); p3 += bhi(u4.y);
        r0 += blo(u5.x); r1 += bhi(u5.x); r2 += blo(u5.y); r3 += bhi(u5.y);
        p0 += blo(u6.x); p1 += bhi(u6.x); p2 += blo(u6.y); p3 += bhi(u6.y);
        r0 += blo(u7.x); r1 += bhi(u7.x); r2 += blo(u7.y); r3 += bhi(u7.y);
    }
    float s0 = p0 + r0, s1 = p1 + r1, s2 = p2 + r2, s3 = p3 + r3;
    float4 bb = *(const float4*)(b2 + 4 * c);
    float4 r;
    r.x = s0 * dn + bb.x;
    r.y = s1 * dn + bb.y;
    r.z = s2 * dn + bb.z;
    r.w = s3 * dn + bb.w;
    *(float4*)(out + (size_t)myNode * OUTC + 4 * c) = r;   // 128B/node, coalesced
}

extern "C" void kernel_launch(void* const* d_in, const int* in_sizes, int n_in,
                              void* d_out, int out_size, void* d_ws, size_t ws_size,
                              hipStream_t stream) {
    const float* x   = (const float*)d_in[0];
    const int*   ei  = (const int*)d_in[1];
    const float* W1  = (const float*)d_in[2];
    const float* b1  = (const float*)d_in[3];
    const float* W2  = (const float*)d_in[4];
    const float* b2  = (const float*)d_in[5];
    float*       out = (float*)d_out;

    const int* srcp = ei;
    const int* dstp = ei + E;

    char* ws = (char*)d_ws;
    int*            bbase  = (int*)(ws + 4096);                // 788 B
    int*            cursor = (int*)(ws + 8192);                // 784 B
    int*            offs   = (int*)(ws + 16384);               // 400,004 B
    float*          dinv   = (float*)(ws + (512u << 10));      // 400 KB
    unsigned*       packed = (unsigned*)(ws + (1u << 20));     // 6.4 MB (becomes csr in place)
    unsigned short* Hs     = (unsigned short*)(ws + (8u << 20));   // 12.8 MB + zero row
    unsigned*       H2u    = (unsigned*)(ws + (21u << 20));    // 6.4 MB + zero row
    int*            csr    = (int*)packed;
    int*            gmat   = (int*)Hs;   // NB*HB ints, dead before k_gemm1 writes Hs

    k_hist <<<HB, 256, 0, stream>>>(dstp, gmat);
    k_bscan<<<1, 256, 0, stream>>>(gmat, bbase, cursor);
    k_part <<<PB, 256, 0, stream>>>(srcp, dstp, cursor, packed);
    k_build<<<NB, 512, 0, stream>>>(bbase, packed, offs, dinv);

    k_gemm1   <<<N / (16 * G1T), 64, 0, stream>>>(x, W1, dinv, Hs);
    k_gather1f<<<N / 16, 256, 0, stream>>>(offs, csr, dinv, Hs, b1, W2, H2u);
    k_gather2 <<<N / 32, 256, 0, stream>>>(offs, csr, dinv, H2u, b2, out);
}

// Round 7
// 224.039 us; speedup vs baseline: 1.1079x; 1.0046x over previous
//
#include <hip/hip_runtime.h>

constexpr int N  = 100000;
constexpr int E  = 1600000;
constexpr int IN = 128, HID = 64, OUTC = 32;

// coarse radix partition params (R6-proven)
constexpr int SHIFT = 9;                       // 512 nodes per bucket
constexpr int NPB   = 1 << SHIFT;              // 512
constexpr int NB    = (N + NPB - 1) / NPB;     // 196 buckets
constexpr int CAP   = 16384;                   // LDS stage cap (mean 8163, sigma~90)
constexpr int PB    = 800;                     // partition blocks (3 blocks/CU)
constexpr int CHUNK = E / PB;                  // 2000 (exact)
constexpr int HB    = 256;                     // hist blocks (gmat columns)
constexpr int G1T   = 5;                       // gemm1 tiles/block (80 rows)

typedef __attribute__((ext_vector_type(8))) short bf16x8_t;  // 8 bf16 (4 VGPR)
typedef __attribute__((ext_vector_type(4))) float f32x4_t;   // 4 fp32

// ---- bf16 helpers ----
__device__ __forceinline__ unsigned short f2bf(float f) {
    union { float f; unsigned int u; } v; v.f = f;
    unsigned int u = v.u;
    return (unsigned short)((u + 0x7fffu + ((u >> 16) & 1u)) >> 16);
}
__device__ __forceinline__ float blo(unsigned u) { return __uint_as_float(u << 16); }
__device__ __forceinline__ float bhi(unsigned u) { return __uint_as_float(u & 0xffff0000u); }

// ---------------- coarse histogram: per-block counts -> gmat[bucket][block] ----------------
__global__ __launch_bounds__(256) void k_hist(const int* __restrict__ dst,
                                              int* __restrict__ gmat) {
    __shared__ int h[NB];
    for (int i = threadIdx.x; i < NB; i += 256) h[i] = 0;
    __syncthreads();
    const int tid = blockIdx.x * 256 + threadIdx.x, nt = HB * 256;
    for (int e = tid; e < E; e += nt) atomicAdd(&h[dst[e] >> SHIFT], 1);
    __syncthreads();
    for (int i = threadIdx.x; i < NB; i += 256)
        gmat[i * HB + blockIdx.x] = h[i];
}

// ---------------- sum gmat rows + scan 196 bucket totals ----------------
__global__ void k_bscan(const int* __restrict__ gmat, int* __restrict__ base,
                        int* __restrict__ cursor) {
    __shared__ int sb[256];
    const int t = threadIdx.x;
    int v = 0;
    if (t < NB) {
        const int4* row = (const int4*)(gmat + t * HB);
        #pragma unroll 8
        for (int j = 0; j < HB / 4; ++j) {
            int4 a = row[j];
            v += (a.x + a.y) + (a.z + a.w);
        }
    }
    sb[t] = v; __syncthreads();
    for (int off = 1; off < 256; off <<= 1) {
        int x = (t >= off) ? sb[t - off] : 0;
        __syncthreads();
        sb[t] += x;
        __syncthreads();
    }
    if (t < NB) { int ex = sb[t] - v; base[t] = ex; cursor[t] = ex; }
    if (t == 0) base[NB] = E;
}

// ---------------- partition edges into coarse buckets ----------------
__global__ __launch_bounds__(256) void k_part(const int* __restrict__ src,
                                              const int* __restrict__ dst,
                                              int* __restrict__ cursor,
                                              unsigned* __restrict__ packed) {
    __shared__ int lh[NB], lb[NB], lc[NB];
    const int t = threadIdx.x;
    const int beg = blockIdx.x * CHUNK, end = beg + CHUNK;
    for (int i = t; i < NB; i += 256) lh[i] = 0;
    __syncthreads();
    for (int e = beg + t; e < end; e += 256) atomicAdd(&lh[dst[e] >> SHIFT], 1);
    __syncthreads();
    for (int i = t; i < NB; i += 256) {
        lb[i] = lh[i] ? atomicAdd(&cursor[i], lh[i]) : 0;
        lc[i] = 0;
    }
    __syncthreads();
    for (int e = beg + t; e < end; e += 256) {
        int d = dst[e], b = d >> SHIFT;
        int idx = atomicAdd(&lc[b], 1);
        packed[lb[b] + idx] = ((unsigned)(d & (NPB - 1)) << 17) | (unsigned)src[e];
    }
}

// ---------------- per-bucket CSR build: offs + dinv + in-place sorted csr ----------------
__global__ __launch_bounds__(512) void k_build(const int* __restrict__ bbase,
                                               unsigned* __restrict__ packed,
                                               int* __restrict__ offs,
                                               float* __restrict__ dinv) {
    __shared__ int cnt[NPB];
    __shared__ unsigned stage[CAP];            // 64 KB
    const int t = threadIdx.x, b = blockIdx.x;
    const int base = bbase[b], cntE = bbase[b + 1] - base;
    const int node0 = b << SHIFT;
    cnt[t] = 0;
    __syncthreads();
    for (int i = t; i < cntE; i += 512) atomicAdd(&cnt[packed[base + i] >> 17], 1);
    __syncthreads();
    const int v = cnt[t];
    __syncthreads();
    for (int off = 1; off < NPB; off <<= 1) {
        int x = (t >= off) ? cnt[t - off] : 0;
        __syncthreads();
        cnt[t] += x;
        __syncthreads();
    }
    const int ex = cnt[t] - v;
    const int node = node0 + t;
    if (node < N) {
        offs[node] = base + ex;
        dinv[node] = rsqrtf((float)v + 1.0f);  // +1 self loop
    }
    if (node == N) offs[N] = E;
    __syncthreads();
    cnt[t] = ex;
    __syncthreads();
    for (int i = t; i < cntE; i += 512) {
        unsigned p = packed[base + i];
        int idx = atomicAdd(&cnt[p >> 17], 1);
        if (idx < CAP) stage[idx] = p & 0x1FFFFu;
    }
    __syncthreads();
    for (int i = t; i < cntE; i += 512)
        packed[base + i] = stage[i];           // in-place: csr == packed buffer
}

// ---------------- GEMM1 via split-bf16 MFMA: Hs = bf16(dinv[row] * (X @ W1)) ----------------
// x = xh + xl, w = wh + wl (bf16 each); X@W ~= xh wh + xl wh + xh wl; fp32 acc.
// 5 tiles of 16 rows per block, W-prep amortized, next-tile A prefetch.
__global__ __launch_bounds__(64) void k_gemm1(const float* __restrict__ X,
                                              const float* __restrict__ W,
                                              const float* __restrict__ dinv,
                                              unsigned short* __restrict__ Hs) {
    const int l    = threadIdx.x;
    const int rlo  = l & 15, khi = l >> 4;     // khi in 0..3
    const int base = blockIdx.x * (16 * G1T);

    // zero-row (index N) for the padded gathers
    if (blockIdx.x == 0 && l < HID / 2)
        ((unsigned*)(Hs + (size_t)N * HID))[l] = 0u;

    // --- prefetch tile 0 A (HBM latency hides under W-prep) ---
    float4 xa[4], xb[4];
    {
        const float* xr = X + (size_t)(base + rlo) * IN + khi * 8;
        #pragma unroll
        for (int ks = 0; ks < 4; ++ks) {
            xa[ks] = *(const float4*)(xr + ks * 32);
            xb[ks] = *(const float4*)(xr + ks * 32 + 4);
        }
    }

    // --- W fragments, split hi/lo: 4 k-steps x 4 col-tiles (once per block) ---
    bf16x8_t wh[4][4], wl[4][4];
    #pragma unroll
    for (int ks = 0; ks < 4; ++ks) {
        #pragma unroll
        for (int ct = 0; ct < 4; ++ct) {
            const float* wp = W + (ks * 32 + khi * 8) * HID + ct * 16 + rlo;
            #pragma unroll
            for (int e = 0; e < 8; ++e) {
                float w = wp[e * HID];
                unsigned short h = f2bf(w);
                float r = w - __uint_as_float((unsigned)h << 16);
                wh[ks][ct][e] = (short)h;
                wl[ks][ct][e] = (short)f2bf(r);
            }
        }
    }

    #pragma unroll
    for (int tile = 0; tile < G1T; ++tile) {
        const int row0 = base + tile * 16;
        float4 cxa[4], cxb[4];
        #pragma unroll
        for (int ks = 0; ks < 4; ++ks) { cxa[ks] = xa[ks]; cxb[ks] = xb[ks]; }
        if (tile + 1 < G1T) {                  // prefetch next tile
            const float* xr = X + (size_t)(row0 + 16 + rlo) * IN + khi * 8;
            #pragma unroll
            for (int ks = 0; ks < 4; ++ks) {
                xa[ks] = *(const float4*)(xr + ks * 32);
                xb[ks] = *(const float4*)(xr + ks * 32 + 4);
            }
        }

        f32x4_t acc[4] = {{0,0,0,0},{0,0,0,0},{0,0,0,0},{0,0,0,0}};
        #pragma unroll
        for (int ks = 0; ks < 4; ++ks) {
            float xr8[8] = {cxa[ks].x, cxa[ks].y, cxa[ks].z, cxa[ks].w,
                            cxb[ks].x, cxb[ks].y, cxb[ks].z, cxb[ks].w};
            bf16x8_t ah, al;
            #pragma unroll
            for (int e = 0; e < 8; ++e) {
                unsigned short h = f2bf(xr8[e]);
                ah[e] = (short)h;
                al[e] = (short)f2bf(xr8[e] - __uint_as_float((unsigned)h << 16));
            }
            #pragma unroll
            for (int ct = 0; ct < 4; ++ct)
                acc[ct] = __builtin_amdgcn_mfma_f32_16x16x32_bf16(ah, wh[ks][ct], acc[ct], 0, 0, 0);
            #pragma unroll
            for (int ct = 0; ct < 4; ++ct)
                acc[ct] = __builtin_amdgcn_mfma_f32_16x16x32_bf16(al, wh[ks][ct], acc[ct], 0, 0, 0);
            #pragma unroll
            for (int ct = 0; ct < 4; ++ct)
                acc[ct] = __builtin_amdgcn_mfma_f32_16x16x32_bf16(ah, wl[ks][ct], acc[ct], 0, 0, 0);
        }

        const int orow = row0 + khi * 4;
        #pragma unroll
        for (int r = 0; r < 4; ++r) {
            const float d = dinv[orow + r];
            #pragma unroll
            for (int ct = 0; ct < 4; ++ct)
                Hs[(size_t)(orow + r) * HID + ct * 16 + rlo] = f2bf(acc[ct][r] * d);
        }
    }
}

// ---------------- gather1 + fused gemm2 ----------------
// EIGHTH-WAVE per node, uint4 (16B) lanes: 8 lanes cover the 128B row,
// 8 nodes/wave, 8 rows in flight each -> 64 rows in flight per wave (2x R6).
// sidx padded to 100 (conflict-free b128), wrow to 68 (conflict-free gemm2).
// Zero-row padding (index N) keeps the loop predication-free.
__global__ __launch_bounds__(256) void k_gather1f(const int* __restrict__ offs,
                                                  const int* __restrict__ csr,
                                                  const float* __restrict__ dinv,
                                                  const unsigned short* __restrict__ Hs,
                                                  const float* __restrict__ b1,
                                                  const float* __restrict__ W2,
                                                  unsigned* __restrict__ H2u) {
    __shared__ float w2s[HID * OUTC];          // 8 KB
    __shared__ int   sidx[4][8][100];          // 12.8 KB
    __shared__ float wrow[4][8][68];           // 8.7 KB
    const int t = threadIdx.x;
    // zero-row (index N) of H2u for k_gather2's padded gather
    if (blockIdx.x == 0 && t < OUTC / 2) H2u[(size_t)N * 16 + t] = 0u;
    for (int i = t; i < HID * OUTC / 4; i += 256)
        ((float4*)w2s)[i] = ((const float4*)W2)[i];
    __syncthreads();

    const int wave = t >> 6, lane = t & 63, q = lane >> 3, c = lane & 7;
    const int myNode = blockIdx.x * 32 + wave * 8 + q;     // N % 32 == 0
    const int o0 = offs[myNode], o1 = offs[myNode + 1];
    const int deg  = o1 - o0;
    const int rdeg = (deg + 7) & ~7;
    for (int i = c; i < deg; i += 8) sidx[wave][q][i] = csr[o0 + i];
    if (c < rdeg - deg) sidx[wave][q][deg + c] = N;        // pad -> zero row

    const uint4* __restrict__ Hu4 = (const uint4*)Hs;      // row = 8 uint4
    const float dn = dinv[myNode];
    uint4 su = Hu4[(size_t)myNode * 8 + c];                // self loop (pre-scaled)
    float p0 = blo(su.x), p1 = bhi(su.x), p2 = blo(su.y), p3 = bhi(su.y);
    float p4 = blo(su.z), p5 = bhi(su.z), p6 = blo(su.w), p7 = bhi(su.w);
    float r0 = 0, r1 = 0, r2 = 0, r3 = 0, r4 = 0, r5 = 0, r6 = 0, r7 = 0;
    for (int k = 0; k < rdeg; k += 8) {
        int4 sa = *(const int4*)&sidx[wave][q][k];         // ds_read_b128
        int4 sb = *(const int4*)&sidx[wave][q][k + 4];     // ds_read_b128
        uint4 u0 = Hu4[(size_t)sa.x * 8 + c];
        uint4 u1 = Hu4[(size_t)sa.y * 8 + c];
        uint4 u2 = Hu4[(size_t)sa.z * 8 + c];
        uint4 u3 = Hu4[(size_t)sa.w * 8 + c];
        uint4 u4 = Hu4[(size_t)sb.x * 8 + c];
        uint4 u5 = Hu4[(size_t)sb.y * 8 + c];
        uint4 u6 = Hu4[(size_t)sb.z * 8 + c];
        uint4 u7 = Hu4[(size_t)sb.w * 8 + c];
        p0 += blo(u0.x); p1 += bhi(u0.x); p2 += blo(u0.y); p3 += bhi(u0.y);
        p4 += blo(u0.z); p5 += bhi(u0.z); p6 += blo(u0.w); p7 += bhi(u0.w);
        r0 += blo(u1.x); r1 += bhi(u1.x); r2 += blo(u1.y); r3 += bhi(u1.y);
        r4 += blo(u1.z); r5 += bhi(u1.z); r6 += blo(u1.w); r7 += bhi(u1.w);
        p0 += blo(u2.x); p1 += bhi(u2.x); p2 += blo(u2.y); p3 += bhi(u2.y);
        p4 += blo(u2.z); p5 += bhi(u2.z); p6 += blo(u2.w); p7 += bhi(u2.w);
        r0 += blo(u3.x); r1 += bhi(u3.x); r2 += blo(u3.y); r3 += bhi(u3.y);
        r4 += blo(u3.z); r5 += bhi(u3.z); r6 += blo(u3.w); r7 += bhi(u3.w);
        p0 += blo(u4.x); p1 += bhi(u4.x); p2 += blo(u4.y); p3 += bhi(u4.y);
        p4 += blo(u4.z); p5 += bhi(u4.z); p6 += blo(u4.w); p7 += bhi(u4.w);
        r0 += blo(u5.x); r1 += bhi(u5.x); r2 += blo(u5.y); r3 += bhi(u5.y);
        r4 += blo(u5.z); r5 += bhi(u5.z); r6 += blo(u5.w); r7 += bhi(u5.w);
        p0 += blo(u6.x); p1 += bhi(u6.x); p2 += blo(u6.y); p3 += bhi(u6.y);
        p4 += blo(u6.z); p5 += bhi(u6.z); p6 += blo(u6.w); p7 += bhi(u6.w);
        r0 += blo(u7.x); r1 += bhi(u7.x); r2 += blo(u7.y); r3 += bhi(u7.y);
        r4 += blo(u7.z); r5 += bhi(u7.z); r6 += blo(u7.w); r7 += bhi(u7.w);
    }
    float s0 = p0 + r0, s1 = p1 + r1, s2 = p2 + r2, s3 = p3 + r3;
    float s4 = p4 + r4, s5 = p5 + r5, s6 = p6 + r6, s7 = p7 + r7;
    float4 ba = *(const float4*)(b1 + 8 * c);
    float4 bbv = *(const float4*)(b1 + 8 * c + 4);
    float4 wv0, wv1;
    wv0.x = fmaxf(s0 * dn + ba.x, 0.0f);                   // fused relu+bias
    wv0.y = fmaxf(s1 * dn + ba.y, 0.0f);
    wv0.z = fmaxf(s2 * dn + ba.z, 0.0f);
    wv0.w = fmaxf(s3 * dn + ba.w, 0.0f);
    wv1.x = fmaxf(s4 * dn + bbv.x, 0.0f);
    wv1.y = fmaxf(s5 * dn + bbv.y, 0.0f);
    wv1.z = fmaxf(s6 * dn + bbv.z, 0.0f);
    wv1.w = fmaxf(s7 * dn + bbv.w, 0.0f);
    *(float4*)&wrow[wave][q][8 * c]     = wv0;
    *(float4*)&wrow[wave][q][8 * c + 4] = wv1;

    // fused gemm2: lane c computes outputs 4c..4c+3 of ITS node (no shuffle)
    float4 acc = {0, 0, 0, 0};
    #pragma unroll
    for (int k = 0; k < HID; k += 4) {
        float4 wr = *(const float4*)&wrow[wave][q][k];
        float4 wa = *(const float4*)&w2s[(k + 0) * OUTC + 4 * c];
        float4 wb = *(const float4*)&w2s[(k + 1) * OUTC + 4 * c];
        float4 wc = *(const float4*)&w2s[(k + 2) * OUTC + 4 * c];
        float4 wd = *(const float4*)&w2s[(k + 3) * OUTC + 4 * c];
        acc.x += wr.x * wa.x + wr.y * wb.x + wr.z * wc.x + wr.w * wd.x;
        acc.y += wr.x * wa.y + wr.y * wb.y + wr.z * wc.y + wr.w * wd.y;
        acc.z += wr.x * wa.z + wr.y * wb.z + wr.z * wc.z + wr.w * wd.z;
        acc.w += wr.x * wa.w + wr.y * wb.w + wr.z * wc.w + wr.w * wd.w;
    }
    uint2 hw;
    hw.x = (unsigned)f2bf(acc.x * dn) | ((unsigned)f2bf(acc.y * dn) << 16);
    hw.y = (unsigned)f2bf(acc.z * dn) | ((unsigned)f2bf(acc.w * dn) << 16);
    ((uint2*)H2u)[(size_t)myNode * 8 + c] = hw;
}

// ---------------- gather2: SIXTEENTH-WAVE per node, uint4 lanes ----------------
// 4 lanes cover the 64B row, 16 nodes/wave, 8 rows in flight each
// -> 128 rows in flight per wave (2x R6). Two float4 output stores per lane.
__global__ __launch_bounds__(256) void k_gather2(const int* __restrict__ offs,
                                                 const int* __restrict__ csr,
                                                 const float* __restrict__ dinv,
                                                 const unsigned* __restrict__ H2u,
                                                 const float* __restrict__ b2,
                                                 float* __restrict__ out) {
    __shared__ int sidx[4][16][100];           // 25.6 KB
    const int t = threadIdx.x;
    const int wave = t >> 6, lane = t & 63, q = lane >> 2, c = lane & 3;
    const int myNode = blockIdx.x * 64 + wave * 16 + q;    // grid = ceil(N/64)
    if (myNode >= N) return;                   // guard BEFORE staging (tail block)
    const int o0 = offs[myNode], o1 = offs[myNode + 1];
    const int deg  = o1 - o0;
    const int rdeg = (deg + 7) & ~7;
    for (int i = c; i < deg; i += 4) sidx[wave][q][i] = csr[o0 + i];
    for (int i = deg + c; i < rdeg; i += 4) sidx[wave][q][i] = N;  // pad -> zero row

    const uint4* __restrict__ H4 = (const uint4*)H2u;      // row = 4 uint4
    const float dn = dinv[myNode];
    uint4 su = H4[(size_t)myNode * 4 + c];                 // self loop (pre-scaled)
    float p0 = blo(su.x), p1 = bhi(su.x), p2 = blo(su.y), p3 = bhi(su.y);
    float p4 = blo(su.z), p5 = bhi(su.z), p6 = blo(su.w), p7 = bhi(su.w);
    float r0 = 0, r1 = 0, r2 = 0, r3 = 0, r4 = 0, r5 = 0, r6 = 0, r7 = 0;
    for (int k = 0; k < rdeg; k += 8) {
        int4 sa = *(const int4*)&sidx[wave][q][k];         // ds_read_b128
        int4 sb = *(const int4*)&sidx[wave][q][k + 4];     // ds_read_b128
        uint4 u0 = H4[(size_t)sa.x * 4 + c];
        uint4 u1 = H4[(size_t)sa.y * 4 + c];
        uint4 u2 = H4[(size_t)sa.z * 4 + c];
        uint4 u3 = H4[(size_t)sa.w * 4 + c];
        uint4 u4 = H4[(size_t)sb.x * 4 + c];
        uint4 u5 = H4[(size_t)sb.y * 4 + c];
        uint4 u6 = H4[(size_t)sb.z * 4 + c];
        uint4 u7 = H4[(size_t)sb.w * 4 + c];
        p0 += blo(u0.x); p1 += bhi(u0.x); p2 += blo(u0.y); p3 += bhi(u0.y);
        p4 += blo(u0.z); p5 += bhi(u0.z); p6 += blo(u0.w); p7 += bhi(u0.w);
        r0 += blo(u1.x); r1 += bhi(u1.x); r2 += blo(u1.y); r3 += bhi(u1.y);
        r4 += blo(u1.z); r5 += bhi(u1.z); r6 += blo(u1.w); r7 += bhi(u1.w);
        p0 += blo(u2.x); p1 += bhi(u2.x); p2 += blo(u2.y); p3 += bhi(u2.y);
        p4 += blo(u2.z); p5 += bhi(u2.z); p6 += blo(u2.w); p7 += bhi(u2.w);
        r0 += blo(u3.x); r1 += bhi(u3.x); r2 += blo(u3.y); r3 += bhi(u3.y);
        r4 += blo(u3.z); r5 += bhi(u3.z); r6 += blo(u3.w); r7 += bhi(u3.w);
        p0 += blo(u4.x); p1 += bhi(u4.x); p2 += blo(u4.y); p3 += bhi(u4.y);
        p4 += blo(u4.z); p5 += bhi(u4.z); p6 += blo(u4.w); p7 += bhi(u4.w);
        r0 += blo(u5.x); r1 += bhi(u5.x); r2 += blo(u5.y); r3 += bhi(u5.y);
        r4 += blo(u5.z); r5 += bhi(u5.z); r6 += blo(u5.w); r7 += bhi(u5.w);
        p0 += blo(u6.x); p1 += bhi(u6.x); p2 += blo(u6.y); p3 += bhi(u6.y);
        p4 += blo(u6.z); p5 += bhi(u6.z); p6 += blo(u6.w); p7 += bhi(u6.w);
        r0 += blo(u7.x); r1 += bhi(u7.x); r2 += blo(u7.y); r3 += bhi(u7.y);
        r4 += blo(u7.z); r5 += bhi(u7.z); r6 += blo(u7.w); r7 += bhi(u7.w);
    }
    float s0 = p0 + r0, s1 = p1 + r1, s2 = p2 + r2, s3 = p3 + r3;
    float s4 = p4 + r4, s5 = p5 + r5, s6 = p6 + r6, s7 = p7 + r7;
    float4 ba = *(const float4*)(b2 + 8 * c);
    float4 bbv = *(const float4*)(b2 + 8 * c + 4);
    float4 o0v, o1v;
    o0v.x = s0 * dn + ba.x;  o0v.y = s1 * dn + ba.y;
    o0v.z = s2 * dn + ba.z;  o0v.w = s3 * dn + ba.w;
    o1v.x = s4 * dn + bbv.x; o1v.y = s5 * dn + bbv.y;
    o1v.z = s6 * dn + bbv.z; o1v.w = s7 * dn + bbv.w;
    float* op = out + (size_t)myNode * OUTC + 8 * c;
    *(float4*)op       = o0v;                              // 128B/node, coalesced
    *(float4*)(op + 4) = o1v;
}

extern "C" void kernel_launch(void* const* d_in, const int* in_sizes, int n_in,
                              void* d_out, int out_size, void* d_ws, size_t ws_size,
                              hipStream_t stream) {
    const float* x   = (const float*)d_in[0];
    const int*   ei  = (const int*)d_in[1];
    const float* W1  = (const float*)d_in[2];
    const float* b1  = (const float*)d_in[3];
    const float* W2  = (const float*)d_in[4];
    const float* b2  = (const float*)d_in[5];
    float*       out = (float*)d_out;

    const int* srcp = ei;
    const int* dstp = ei + E;

    char* ws = (char*)d_ws;
    int*            bbase  = (int*)(ws + 4096);                // 788 B
    int*            cursor = (int*)(ws + 8192);                // 784 B
    int*            offs   = (int*)(ws + 16384);               // 400,004 B
    float*          dinv   = (float*)(ws + (512u << 10));      // 400 KB
    unsigned*       packed = (unsigned*)(ws + (1u << 20));     // 6.4 MB (becomes csr in place)
    unsigned short* Hs     = (unsigned short*)(ws + (8u << 20));   // 12.8 MB + zero row
    unsigned*       H2u    = (unsigned*)(ws + (21u << 20));    // 6.4 MB + zero row
    int*            csr    = (int*)packed;
    int*            gmat   = (int*)Hs;   // NB*HB ints, dead before k_gemm1 writes Hs

    k_hist <<<HB, 256, 0, stream>>>(dstp, gmat);
    k_bscan<<<1, 256, 0, stream>>>(gmat, bbase, cursor);
    k_part <<<PB, 256, 0, stream>>>(srcp, dstp, cursor, packed);
    k_build<<<NB, 512, 0, stream>>>(bbase, packed, offs, dinv);

    k_gemm1   <<<N / (16 * G1T), 64, 0, stream>>>(x, W1, dinv, Hs);
    k_gather1f<<<N / 32, 256, 0, stream>>>(offs, csr, dinv, Hs, b1, W2, H2u);
    k_gather2 <<<(N + 63) / 64, 256, 0, stream>>>(offs, csr, dinv, H2u, b2, out);
}

// Round 9
// 221.592 us; speedup vs baseline: 1.1202x; 1.0110x over previous
//
#include <hip/hip_runtime.h>

constexpr int N  = 100000;
constexpr int E  = 1600000;
constexpr int IN = 128, HID = 64, OUTC = 32;

// coarse radix partition params (R6-proven)
constexpr int SHIFT = 9;                       // 512 nodes per bucket
constexpr int NPB   = 1 << SHIFT;              // 512
constexpr int NB    = (N + NPB - 1) / NPB;     // 196 buckets
constexpr int CAP   = 16384;                   // LDS stage cap (mean 8163, sigma~90)
constexpr int PB    = 800;                     // partition blocks (3 blocks/CU)
constexpr int CHUNK = E / PB;                  // 2000 (exact)
constexpr int HB    = 256;                     // hist blocks (gmat columns)

typedef __attribute__((ext_vector_type(8))) short bf16x8_t;  // 8 bf16 (4 VGPR)
typedef __attribute__((ext_vector_type(4))) float f32x4_t;   // 4 fp32

// ---- bf16 helpers ----
__device__ __forceinline__ unsigned short f2bf(float f) {
    union { float f; unsigned int u; } v; v.f = f;
    unsigned int u = v.u;
    return (unsigned short)((u + 0x7fffu + ((u >> 16) & 1u)) >> 16);
}
__device__ __forceinline__ float blo(unsigned u) { return __uint_as_float(u << 16); }
__device__ __forceinline__ float bhi(unsigned u) { return __uint_as_float(u & 0xffff0000u); }

// ---------------- coarse histogram: per-block counts -> gmat[bucket][block] ----------------
__global__ __launch_bounds__(256) void k_hist(const int* __restrict__ dst,
                                              int* __restrict__ gmat) {
    __shared__ int h[NB];
    for (int i = threadIdx.x; i < NB; i += 256) h[i] = 0;
    __syncthreads();
    const int tid = blockIdx.x * 256 + threadIdx.x, nt = HB * 256;
    for (int e = tid; e < E; e += nt) atomicAdd(&h[dst[e] >> SHIFT], 1);
    __syncthreads();
    for (int i = threadIdx.x; i < NB; i += 256)
        gmat[i * HB + blockIdx.x] = h[i];
}

// ---------------- sum gmat rows + scan 196 bucket totals ----------------
__global__ void k_bscan(const int* __restrict__ gmat, int* __restrict__ base,
                        int* __restrict__ cursor) {
    __shared__ int sb[256];
    const int t = threadIdx.x;
    int v = 0;
    if (t < NB) {
        const int4* row = (const int4*)(gmat + t * HB);
        #pragma unroll 8
        for (int j = 0; j < HB / 4; ++j) {
            int4 a = row[j];
            v += (a.x + a.y) + (a.z + a.w);
        }
    }
    sb[t] = v; __syncthreads();
    for (int off = 1; off < 256; off <<= 1) {
        int x = (t >= off) ? sb[t - off] : 0;
        __syncthreads();
        sb[t] += x;
        __syncthreads();
    }
    if (t < NB) { int ex = sb[t] - v; base[t] = ex; cursor[t] = ex; }
    if (t == 0) base[NB] = E;
}

// ---------------- partition edges into coarse buckets ----------------
__global__ __launch_bounds__(256) void k_part(const int* __restrict__ src,
                                              const int* __restrict__ dst,
                                              int* __restrict__ cursor,
                                              unsigned* __restrict__ packed) {
    __shared__ int lh[NB], lb[NB], lc[NB];
    const int t = threadIdx.x;
    const int beg = blockIdx.x * CHUNK, end = beg + CHUNK;
    for (int i = t; i < NB; i += 256) lh[i] = 0;
    __syncthreads();
    for (int e = beg + t; e < end; e += 256) atomicAdd(&lh[dst[e] >> SHIFT], 1);
    __syncthreads();
    for (int i = t; i < NB; i += 256) {
        lb[i] = lh[i] ? atomicAdd(&cursor[i], lh[i]) : 0;
        lc[i] = 0;
    }
    __syncthreads();
    for (int e = beg + t; e < end; e += 256) {
        int d = dst[e], b = d >> SHIFT;
        int idx = atomicAdd(&lc[b], 1);
        packed[lb[b] + idx] = ((unsigned)(d & (NPB - 1)) << 17) | (unsigned)src[e];
    }
}

// ---------------- per-bucket CSR build: offs + dinv + in-place sorted csr ----------------
__global__ __launch_bounds__(512) void k_build(const int* __restrict__ bbase,
                                               unsigned* __restrict__ packed,
                                               int* __restrict__ offs,
                                               float* __restrict__ dinv) {
    __shared__ int cnt[NPB];
    __shared__ unsigned stage[CAP];            // 64 KB
    const int t = threadIdx.x, b = blockIdx.x;
    const int base = bbase[b], cntE = bbase[b + 1] - base;
    const int node0 = b << SHIFT;
    cnt[t] = 0;
    __syncthreads();
    for (int i = t; i < cntE; i += 512) atomicAdd(&cnt[packed[base + i] >> 17], 1);
    __syncthreads();
    const int v = cnt[t];
    __syncthreads();
    for (int off = 1; off < NPB; off <<= 1) {
        int x = (t >= off) ? cnt[t - off] : 0;
        __syncthreads();
        cnt[t] += x;
        __syncthreads();
    }
    const int ex = cnt[t] - v;
    const int node = node0 + t;
    if (node < N) {
        offs[node] = base + ex;
        dinv[node] = rsqrtf((float)v + 1.0f);  // +1 self loop
    }
    if (node == N) offs[N] = E;
    __syncthreads();
    cnt[t] = ex;
    __syncthreads();
    for (int i = t; i < cntE; i += 512) {
        unsigned p = packed[base + i];
        int idx = atomicAdd(&cnt[p >> 17], 1);
        if (idx < CAP) stage[idx] = p & 0x1FFFFu;
    }
    __syncthreads();
    for (int i = t; i < cntE; i += 512)
        packed[base + i] = stage[i];           // in-place: csr == packed buffer
}

// ---------------- GEMM1 via split-bf16 MFMA: Hs = bf16(dinv[row] * (X @ W1)) ----------------
// x = xh + xl, w = wh + wl (bf16 each); X@W ~= xh wh + xl wh + xh wl; fp32 acc.
// OCCUPANCY FIX (R7: 1250 one-wave blocks = 4.9 waves/CU, 12.7% occ, latency-
// bound at 59us): 256-thread blocks, ONE 16-row tile per wave, grid 1563 ->
// 6250 independent waves, ~16 waves/CU (VGPR-capped). X loads issued first;
// W-prep (independent) covers their latency; MFMA order unchanged (bit-identical).
__global__ __launch_bounds__(256, 4) void k_gemm1(const float* __restrict__ X,
                                                  const float* __restrict__ W,
                                                  const float* __restrict__ dinv,
                                                  unsigned short* __restrict__ Hs) {
    const int t = threadIdx.x;
    // zero-row (index N) for the padded gathers
    if (blockIdx.x == 0 && t < HID / 2)
        ((unsigned*)(Hs + (size_t)N * HID))[t] = 0u;

    const int wave = t >> 6, l = t & 63;
    const int rlo  = l & 15, khi = l >> 4;     // khi in 0..3
    const int row0 = (blockIdx.x * 4 + wave) * 16;
    if (row0 >= N) return;                     // tail tiles (N % 16 == 0)

    // --- issue A-tile loads first (latency hides under W-prep) ---
    const float* xr = X + (size_t)(row0 + rlo) * IN + khi * 8;
    float4 xa[4], xb[4];
    #pragma unroll
    for (int ks = 0; ks < 4; ++ks) {
        xa[ks] = *(const float4*)(xr + ks * 32);
        xb[ks] = *(const float4*)(xr + ks * 32 + 4);
    }

    // --- W fragments, split hi/lo: 4 k-steps x 4 col-tiles ---
    bf16x8_t wh[4][4], wl[4][4];
    #pragma unroll
    for (int ks = 0; ks < 4; ++ks) {
        #pragma unroll
        for (int ct = 0; ct < 4; ++ct) {
            const float* wp = W + (ks * 32 + khi * 8) * HID + ct * 16 + rlo;
            #pragma unroll
            for (int e = 0; e < 8; ++e) {
                float w = wp[e * HID];
                unsigned short h = f2bf(w);
                float r = w - __uint_as_float((unsigned)h << 16);
                wh[ks][ct][e] = (short)h;
                wl[ks][ct][e] = (short)f2bf(r);
            }
        }
    }

    f32x4_t acc[4] = {{0,0,0,0},{0,0,0,0},{0,0,0,0},{0,0,0,0}};
    #pragma unroll
    for (int ks = 0; ks < 4; ++ks) {
        float xr8[8] = {xa[ks].x, xa[ks].y, xa[ks].z, xa[ks].w,
                        xb[ks].x, xb[ks].y, xb[ks].z, xb[ks].w};
        bf16x8_t ah, al;
        #pragma unroll
        for (int e = 0; e < 8; ++e) {
            unsigned short h = f2bf(xr8[e]);
            ah[e] = (short)h;
            al[e] = (short)f2bf(xr8[e] - __uint_as_float((unsigned)h << 16));
        }
        #pragma unroll
        for (int ct = 0; ct < 4; ++ct)
            acc[ct] = __builtin_amdgcn_mfma_f32_16x16x32_bf16(ah, wh[ks][ct], acc[ct], 0, 0, 0);
        #pragma unroll
        for (int ct = 0; ct < 4; ++ct)
            acc[ct] = __builtin_amdgcn_mfma_f32_16x16x32_bf16(al, wh[ks][ct], acc[ct], 0, 0, 0);
        #pragma unroll
        for (int ct = 0; ct < 4; ++ct)
            acc[ct] = __builtin_amdgcn_mfma_f32_16x16x32_bf16(ah, wl[ks][ct], acc[ct], 0, 0, 0);
    }

    // --- epilogue: scale by dinv, pack bf16, store ---
    const int orow = row0 + khi * 4;
    #pragma unroll
    for (int r = 0; r < 4; ++r) {
        const float d = dinv[orow + r];
        #pragma unroll
        for (int ct = 0; ct < 4; ++ct)
            Hs[(size_t)(orow + r) * HID + ct * 16 + rlo] = f2bf(acc[ct][r] * d);
    }
}

// ---------------- gather1 + fused gemm2 ----------------
// EIGHTH-WAVE per node, uint4 (16B) lanes: 8 lanes cover the 128B row,
// 8 nodes/wave, 8 rows in flight each -> 64 rows in flight per wave.
// sidx padded to 100 (conflict-free b128), wrow to 68 (conflict-free gemm2).
// Zero-row padding (index N) keeps the loop predication-free.
__global__ __launch_bounds__(256) void k_gather1f(const int* __restrict__ offs,
                                                  const int* __restrict__ csr,
                                                  const float* __restrict__ dinv,
                                                  const unsigned short* __restrict__ Hs,
                                                  const float* __restrict__ b1,
                                                  const float* __restrict__ W2,
                                                  unsigned* __restrict__ H2u) {
    __shared__ float w2s[HID * OUTC];          // 8 KB
    __shared__ int   sidx[4][8][100];          // 12.8 KB
    __shared__ float wrow[4][8][68];           // 8.7 KB
    const int t = threadIdx.x;
    // zero-row (index N) of H2u for k_gather2's padded gather
    if (blockIdx.x == 0 && t < OUTC / 2) H2u[(size_t)N * 16 + t] = 0u;
    for (int i = t; i < HID * OUTC / 4; i += 256)
        ((float4*)w2s)[i] = ((const float4*)W2)[i];
    __syncthreads();

    const int wave = t >> 6, lane = t & 63, q = lane >> 3, c = lane & 7;
    const int myNode = blockIdx.x * 32 + wave * 8 + q;     // N % 32 == 0
    const int o0 = offs[myNode], o1 = offs[myNode + 1];
    const int deg  = o1 - o0;
    const int rdeg = (deg + 7) & ~7;
    for (int i = c; i < deg; i += 8) sidx[wave][q][i] = csr[o0 + i];
    if (c < rdeg - deg) sidx[wave][q][deg + c] = N;        // pad -> zero row

    const uint4* __restrict__ Hu4 = (const uint4*)Hs;      // row = 8 uint4
    const float dn = dinv[myNode];
    uint4 su = Hu4[(size_t)myNode * 8 + c];                // self loop (pre-scaled)
    float p0 = blo(su.x), p1 = bhi(su.x), p2 = blo(su.y), p3 = bhi(su.y);
    float p4 = blo(su.z), p5 = bhi(su.z), p6 = blo(su.w), p7 = bhi(su.w);
    float r0 = 0, r1 = 0, r2 = 0, r3 = 0, r4 = 0, r5 = 0, r6 = 0, r7 = 0;
    for (int k = 0; k < rdeg; k += 8) {
        int4 sa = *(const int4*)&sidx[wave][q][k];         // ds_read_b128
        int4 sb = *(const int4*)&sidx[wave][q][k + 4];     // ds_read_b128
        uint4 u0 = Hu4[(size_t)sa.x * 8 + c];
        uint4 u1 = Hu4[(size_t)sa.y * 8 + c];
        uint4 u2 = Hu4[(size_t)sa.z * 8 + c];
        uint4 u3 = Hu4[(size_t)sa.w * 8 + c];
        uint4 u4 = Hu4[(size_t)sb.x * 8 + c];
        uint4 u5 = Hu4[(size_t)sb.y * 8 + c];
        uint4 u6 = Hu4[(size_t)sb.z * 8 + c];
        uint4 u7 = Hu4[(size_t)sb.w * 8 + c];
        p0 += blo(u0.x); p1 += bhi(u0.x); p2 += blo(u0.y); p3 += bhi(u0.y);
        p4 += blo(u0.z); p5 += bhi(u0.z); p6 += blo(u0.w); p7 += bhi(u0.w);
        r0 += blo(u1.x); r1 += bhi(u1.x); r2 += blo(u1.y); r3 += bhi(u1.y);
        r4 += blo(u1.z); r5 += bhi(u1.z); r6 += blo(u1.w); r7 += bhi(u1.w);
        p0 += blo(u2.x); p1 += bhi(u2.x); p2 += blo(u2.y); p3 += bhi(u2.y);
        p4 += blo(u2.z); p5 += bhi(u2.z); p6 += blo(u2.w); p7 += bhi(u2.w);
        r0 += blo(u3.x); r1 += bhi(u3.x); r2 += blo(u3.y); r3 += bhi(u3.y);
        r4 += blo(u3.z); r5 += bhi(u3.z); r6 += blo(u3.w); r7 += bhi(u3.w);
        p0 += blo(u4.x); p1 += bhi(u4.x); p2 += blo(u4.y); p3 += bhi(u4.y);
        p4 += blo(u4.z); p5 += bhi(u4.z); p6 += blo(u4.w); p7 += bhi(u4.w);
        r0 += blo(u5.x); r1 += bhi(u5.x); r2 += blo(u5.y); r3 += bhi(u5.y);
        r4 += blo(u5.z); r5 += bhi(u5.z); r6 += blo(u5.w); r7 += bhi(u5.w);
        p0 += blo(u6.x); p1 += bhi(u6.x); p2 += blo(u6.y); p3 += bhi(u6.y);
        p4 += blo(u6.z); p5 += bhi(u6.z); p6 += blo(u6.w); p7 += bhi(u6.w);
        r0 += blo(u7.x); r1 += bhi(u7.x); r2 += blo(u7.y); r3 += bhi(u7.y);
        r4 += blo(u7.z); r5 += bhi(u7.z); r6 += blo(u7.w); r7 += bhi(u7.w);
    }
    float s0 = p0 + r0, s1 = p1 + r1, s2 = p2 + r2, s3 = p3 + r3;
    float s4 = p4 + r4, s5 = p5 + r5, s6 = p6 + r6, s7 = p7 + r7;
    float4 ba = *(const float4*)(b1 + 8 * c);
    float4 bbv = *(const float4*)(b1 + 8 * c + 4);
    float4 wv0, wv1;
    wv0.x = fmaxf(s0 * dn + ba.x, 0.0f);                   // fused relu+bias
    wv0.y = fmaxf(s1 * dn + ba.y, 0.0f);
    wv0.z = fmaxf(s2 * dn + ba.z, 0.0f);
    wv0.w = fmaxf(s3 * dn + ba.w, 0.0f);
    wv1.x = fmaxf(s4 * dn + bbv.x, 0.0f);
    wv1.y = fmaxf(s5 * dn + bbv.y, 0.0f);
    wv1.z = fmaxf(s6 * dn + bbv.z, 0.0f);
    wv1.w = fmaxf(s7 * dn + bbv.w, 0.0f);
    *(float4*)&wrow[wave][q][8 * c]     = wv0;
    *(float4*)&wrow[wave][q][8 * c + 4] = wv1;

    // fused gemm2: lane c computes outputs 4c..4c+3 of ITS node (no shuffle)
    float4 acc = {0, 0, 0, 0};
    #pragma unroll
    for (int k = 0; k < HID; k += 4) {
        float4 wr = *(const float4*)&wrow[wave][q][k];
        float4 wa = *(const float4*)&w2s[(k + 0) * OUTC + 4 * c];
        float4 wb = *(const float4*)&w2s[(k + 1) * OUTC + 4 * c];
        float4 wc = *(const float4*)&w2s[(k + 2) * OUTC + 4 * c];
        float4 wd = *(const float4*)&w2s[(k + 3) * OUTC + 4 * c];
        acc.x += wr.x * wa.x + wr.y * wb.x + wr.z * wc.x + wr.w * wd.x;
        acc.y += wr.x * wa.y + wr.y * wb.y + wr.z * wc.y + wr.w * wd.y;
        acc.z += wr.x * wa.z + wr.y * wb.z + wr.z * wc.z + wr.w * wd.z;
        acc.w += wr.x * wa.w + wr.y * wb.w + wr.z * wc.w + wr.w * wd.w;
    }
    uint2 hw;
    hw.x = (unsigned)f2bf(acc.x * dn) | ((unsigned)f2bf(acc.y * dn) << 16);
    hw.y = (unsigned)f2bf(acc.z * dn) | ((unsigned)f2bf(acc.w * dn) << 16);
    ((uint2*)H2u)[(size_t)myNode * 8 + c] = hw;
}

// ---------------- gather2: SIXTEENTH-WAVE per node, uint4 lanes ----------------
// 4 lanes cover the 64B row, 16 nodes/wave, 8 rows in flight each
// -> 128 rows in flight per wave. Two float4 output stores per lane.
__global__ __launch_bounds__(256) void k_gather2(const int* __restrict__ offs,
                                                 const int* __restrict__ csr,
                                                 const float* __restrict__ dinv,
                                                 const unsigned* __restrict__ H2u,
                                                 const float* __restrict__ b2,
                                                 float* __restrict__ out) {
    __shared__ int sidx[4][16][100];           // 25.6 KB
    const int t = threadIdx.x;
    const int wave = t >> 6, lane = t & 63, q = lane >> 2, c = lane & 3;
    const int myNode = blockIdx.x * 64 + wave * 16 + q;    // grid = ceil(N/64)
    if (myNode >= N) return;                   // guard BEFORE staging (tail block)
    const int o0 = offs[myNode], o1 = offs[myNode + 1];
    const int deg  = o1 - o0;
    const int rdeg = (deg + 7) & ~7;
    for (int i = c; i < deg; i += 4) sidx[wave][q][i] = csr[o0 + i];
    for (int i = deg + c; i < rdeg; i += 4) sidx[wave][q][i] = N;  // pad -> zero row

    const uint4* __restrict__ H4 = (const uint4*)H2u;      // row = 4 uint4
    const float dn = dinv[myNode];
    uint4 su = H4[(size_t)myNode * 4 + c];                 // self loop (pre-scaled)
    float p0 = blo(su.x), p1 = bhi(su.x), p2 = blo(su.y), p3 = bhi(su.y);
    float p4 = blo(su.z), p5 = bhi(su.z), p6 = blo(su.w), p7 = bhi(su.w);
    float r0 = 0, r1 = 0, r2 = 0, r3 = 0, r4 = 0, r5 = 0, r6 = 0, r7 = 0;
    for (int k = 0; k < rdeg; k += 8) {
        int4 sa = *(const int4*)&sidx[wave][q][k];         // ds_read_b128
        int4 sb = *(const int4*)&sidx[wave][q][k + 4];     // ds_read_b128
        uint4 u0 = H4[(size_t)sa.x * 4 + c];
        uint4 u1 = H4[(size_t)sa.y * 4 + c];
        uint4 u2 = H4[(size_t)sa.z * 4 + c];
        uint4 u3 = H4[(size_t)sa.w * 4 + c];
        uint4 u4 = H4[(size_t)sb.x * 4 + c];
        uint4 u5 = H4[(size_t)sb.y * 4 + c];
        uint4 u6 = H4[(size_t)sb.z * 4 + c];
        uint4 u7 = H4[(size_t)sb.w * 4 + c];
        p0 += blo(u0.x); p1 += bhi(u0.x); p2 += blo(u0.y); p3 += bhi(u0.y);
        p4 += blo(u0.z); p5 += bhi(u0.z); p6 += blo(u0.w); p7 += bhi(u0.w);
        r0 += blo(u1.x); r1 += bhi(u1.x); r2 += blo(u1.y); r3 += bhi(u1.y);
        r4 += blo(u1.z); r5 += bhi(u1.z); r6 += blo(u1.w); r7 += bhi(u1.w);
        p0 += blo(u2.x); p1 += bhi(u2.x); p2 += blo(u2.y); p3 += bhi(u2.y);
        p4 += blo(u2.z); p5 += bhi(u2.z); p6 += blo(u2.w); p7 += bhi(u2.w);
        r0 += blo(u3.x); r1 += bhi(u3.x); r2 += blo(u3.y); r3 += bhi(u3.y);
        r4 += blo(u3.z); r5 += bhi(u3.z); r6 += blo(u3.w); r7 += bhi(u3.w);
        p0 += blo(u4.x); p1 += bhi(u4.x); p2 += blo(u4.y); p3 += bhi(u4.y);
        p4 += blo(u4.z); p5 += bhi(u4.z); p6 += blo(u4.w); p7 += bhi(u4.w);
        r0 += blo(u5.x); r1 += bhi(u5.x); r2 += blo(u5.y); r3 += bhi(u5.y);
        r4 += blo(u5.z); r5 += bhi(u5.z); r6 += blo(u5.w); r7 += bhi(u5.w);
        p0 += blo(u6.x); p1 += bhi(u6.x); p2 += blo(u6.y); p3 += bhi(u6.y);
        p4 += blo(u6.z); p5 += bhi(u6.z); p6 += blo(u6.w); p7 += bhi(u6.w);
        r0 += blo(u7.x); r1 += bhi(u7.x); r2 += blo(u7.y); r3 += bhi(u7.y);
        r4 += blo(u7.z); r5 += bhi(u7.z); r6 += blo(u7.w); r7 += bhi(u7.w);
    }
    float s0 = p0 + r0, s1 = p1 + r1, s2 = p2 + r2, s3 = p3 + r3;
    float s4 = p4 + r4, s5 = p5 + r5, s6 = p6 + r6, s7 = p7 + r7;
    float4 ba = *(const float4*)(b2 + 8 * c);
    float4 bbv = *(const float4*)(b2 + 8 * c + 4);
    float4 o0v, o1v;
    o0v.x = s0 * dn + ba.x;  o0v.y = s1 * dn + ba.y;
    o0v.z = s2 * dn + ba.z;  o0v.w = s3 * dn + ba.w;
    o1v.x = s4 * dn + bbv.x; o1v.y = s5 * dn + bbv.y;
    o1v.z = s6 * dn + bbv.z; o1v.w = s7 * dn + bbv.w;
    float* op = out + (size_t)myNode * OUTC + 8 * c;
    *(float4*)op       = o0v;                              // 128B/node, coalesced
    *(float4*)(op + 4) = o1v;
}

extern "C" void kernel_launch(void* const* d_in, const int* in_sizes, int n_in,
                              void* d_out, int out_size, void* d_ws, size_t ws_size,
                              hipStream_t stream) {
    const float* x   = (const float*)d_in[0];
    const int*   ei  = (const int*)d_in[1];
    const float* W1  = (const float*)d_in[2];
    const float* b1  = (const float*)d_in[3];
    const float* W2  = (const float*)d_in[4];
    const float* b2  = (const float*)d_in[5];
    float*       out = (float*)d_out;

    const int* srcp = ei;
    const int* dstp = ei + E;

    char* ws = (char*)d_ws;
    int*            bbase  = (int*)(ws + 4096);                // 788 B
    int*            cursor = (int*)(ws + 8192);                // 784 B
    int*            offs   = (int*)(ws + 16384);               // 400,004 B
    float*          dinv   = (float*)(ws + (512u << 10));      // 400 KB
    unsigned*       packed = (unsigned*)(ws + (1u << 20));     // 6.4 MB (becomes csr in place)
    unsigned short* Hs     = (unsigned short*)(ws + (8u << 20));   // 12.8 MB + zero row
    unsigned*       H2u    = (unsigned*)(ws + (21u << 20));    // 6.4 MB + zero row
    int*            csr    = (int*)packed;
    int*            gmat   = (int*)Hs;   // NB*HB ints, dead before k_gemm1 writes Hs

    k_hist <<<HB, 256, 0, stream>>>(dstp, gmat);
    k_bscan<<<1, 256, 0, stream>>>(gmat, bbase, cursor);
    k_part <<<PB, 256, 0, stream>>>(srcp, dstp, cursor, packed);
    k_build<<<NB, 512, 0, stream>>>(bbase, packed, offs, dinv);

    k_gemm1   <<<(N / 16 + 3) / 4, 256, 0, stream>>>(x, W1, dinv, Hs);
    k_gather1f<<<N / 32, 256, 0, stream>>>(offs, csr, dinv, Hs, b1, W2, H2u);
    k_gather2 <<<(N + 63) / 64, 256, 0, stream>>>(offs, csr, dinv, H2u, b2, out);
}

// Round 10
// 216.614 us; speedup vs baseline: 1.1459x; 1.0230x over previous
//
#include <hip/hip_runtime.h>

constexpr int N  = 100000;
constexpr int E  = 1600000;
constexpr int IN = 128, HID = 64, OUTC = 32;

// coarse radix partition params
constexpr int SHIFT = 9;                       // 512 nodes per bucket
constexpr int NPB   = 1 << SHIFT;              // 512
constexpr int NB    = (N + NPB - 1) / NPB;     // 196 buckets
constexpr int CAP   = 16384;                   // LDS stage cap
constexpr int CAPB  = 9216;                    // fixed bucket stride (mean 8192, +11 sigma)
constexpr int PB    = 800;                     // partition blocks (3 blocks/CU)
constexpr int CHUNK = E / PB;                  // 2000 (exact)

typedef __attribute__((ext_vector_type(8))) short bf16x8_t;  // 8 bf16 (4 VGPR)
typedef __attribute__((ext_vector_type(4))) float f32x4_t;   // 4 fp32

// ---- bf16 helpers ----
__device__ __forceinline__ unsigned short f2bf(float f) {
    union { float f; unsigned int u; } v; v.f = f;
    unsigned int u = v.u;
    return (unsigned short)((u + 0x7fffu + ((u >> 16) & 1u)) >> 16);
}
__device__ __forceinline__ float blo(unsigned u) { return __uint_as_float(u << 16); }
__device__ __forceinline__ float bhi(unsigned u) { return __uint_as_float(u & 0xffff0000u); }

// ---------------- partition edges into FIXED-STRIDE coarse buckets ----------------
// No pre-computed bases: bucket b owns packed[b*CAPB .. b*CAPB+CAPB); blocks
// reserve ranges via atomicAdd on cursor[b] (zeroed by a tiny memset).
// Replaces the old k_hist + k_bscan dispatches entirely.
__global__ __launch_bounds__(256) void k_part(const int* __restrict__ src,
                                              const int* __restrict__ dst,
                                              int* __restrict__ cursor,
                                              unsigned* __restrict__ packed) {
    __shared__ int lh[NB], lb[NB], lc[NB];
    const int t = threadIdx.x;
    const int beg = blockIdx.x * CHUNK, end = beg + CHUNK;
    for (int i = t; i < NB; i += 256) lh[i] = 0;
    __syncthreads();
    for (int e = beg + t; e < end; e += 256) atomicAdd(&lh[dst[e] >> SHIFT], 1);
    __syncthreads();
    for (int i = t; i < NB; i += 256) {
        lb[i] = lh[i] ? (i * CAPB + atomicAdd(&cursor[i], lh[i])) : 0;
        lc[i] = 0;
    }
    __syncthreads();
    for (int e = beg + t; e < end; e += 256) {
        int d = dst[e], b = d >> SHIFT;
        int idx = atomicAdd(&lc[b], 1);
        packed[lb[b] + idx] = ((unsigned)(d & (NPB - 1)) << 17) | (unsigned)src[e];
    }
}

// ---------------- per-bucket CSR build: offs/offsEnd + dinv + in-place sorted csr ----------------
// base = b*CAPB (fixed stride); cntE = cursor[b] (filled by k_part).
// offsEnd[node] makes degree computation immune to bucket-boundary slack.
__global__ __launch_bounds__(512) void k_build(const int* __restrict__ cursor,
                                               unsigned* __restrict__ packed,
                                               int* __restrict__ offs,
                                               int* __restrict__ offsE,
                                               float* __restrict__ dinv) {
    __shared__ int cnt[NPB];
    __shared__ unsigned stage[CAP];            // 64 KB
    const int t = threadIdx.x, b = blockIdx.x;
    const int base = b * CAPB, cntE = cursor[b];
    const int node0 = b << SHIFT;
    cnt[t] = 0;
    __syncthreads();
    for (int i = t; i < cntE; i += 512) atomicAdd(&cnt[packed[base + i] >> 17], 1);
    __syncthreads();
    const int v = cnt[t];
    __syncthreads();
    for (int off = 1; off < NPB; off <<= 1) {
        int x = (t >= off) ? cnt[t - off] : 0;
        __syncthreads();
        cnt[t] += x;
        __syncthreads();
    }
    const int ex = cnt[t] - v;
    const int node = node0 + t;
    if (node < N) {
        offs[node]  = base + ex;
        offsE[node] = base + ex + v;
        dinv[node]  = rsqrtf((float)v + 1.0f); // +1 self loop
    }
    __syncthreads();
    cnt[t] = ex;
    __syncthreads();
    for (int i = t; i < cntE; i += 512) {
        unsigned p = packed[base + i];
        int idx = atomicAdd(&cnt[p >> 17], 1);
        if (idx < CAP) stage[idx] = p & 0x1FFFFu;
    }
    __syncthreads();
    for (int i = t; i < cntE; i += 512)
        packed[base + i] = stage[i];           // in-place: csr == packed buffer
}

// ---------------- GEMM1 via split-bf16 MFMA: Hs = bf16(dinv[row] * (X @ W1)) ----------------
// x = xh + xl, w = wh + wl (bf16 each); X@W ~= xh wh + xl wh + xh wl; fp32 acc.
// 256-thread blocks, ONE 16-row tile per wave -> 6250 independent waves,
// ~16 waves/CU (VGPR-capped). X loads issued first; W-prep covers their latency.
__global__ __launch_bounds__(256, 4) void k_gemm1(const float* __restrict__ X,
                                                  const float* __restrict__ W,
                                                  const float* __restrict__ dinv,
                                                  unsigned short* __restrict__ Hs) {
    const int t = threadIdx.x;
    // zero-row (index N) for the padded gathers
    if (blockIdx.x == 0 && t < HID / 2)
        ((unsigned*)(Hs + (size_t)N * HID))[t] = 0u;

    const int wave = t >> 6, l = t & 63;
    const int rlo  = l & 15, khi = l >> 4;     // khi in 0..3
    const int row0 = (blockIdx.x * 4 + wave) * 16;
    if (row0 >= N) return;                     // tail tiles (N % 16 == 0)

    // --- issue A-tile loads first (latency hides under W-prep) ---
    const float* xr = X + (size_t)(row0 + rlo) * IN + khi * 8;
    float4 xa[4], xb[4];
    #pragma unroll
    for (int ks = 0; ks < 4; ++ks) {
        xa[ks] = *(const float4*)(xr + ks * 32);
        xb[ks] = *(const float4*)(xr + ks * 32 + 4);
    }

    // --- W fragments, split hi/lo: 4 k-steps x 4 col-tiles ---
    bf16x8_t wh[4][4], wl[4][4];
    #pragma unroll
    for (int ks = 0; ks < 4; ++ks) {
        #pragma unroll
        for (int ct = 0; ct < 4; ++ct) {
            const float* wp = W + (ks * 32 + khi * 8) * HID + ct * 16 + rlo;
            #pragma unroll
            for (int e = 0; e < 8; ++e) {
                float w = wp[e * HID];
                unsigned short h = f2bf(w);
                float r = w - __uint_as_float((unsigned)h << 16);
                wh[ks][ct][e] = (short)h;
                wl[ks][ct][e] = (short)f2bf(r);
            }
        }
    }

    f32x4_t acc[4] = {{0,0,0,0},{0,0,0,0},{0,0,0,0},{0,0,0,0}};
    #pragma unroll
    for (int ks = 0; ks < 4; ++ks) {
        float xr8[8] = {xa[ks].x, xa[ks].y, xa[ks].z, xa[ks].w,
                        xb[ks].x, xb[ks].y, xb[ks].z, xb[ks].w};
        bf16x8_t ah, al;
        #pragma unroll
        for (int e = 0; e < 8; ++e) {
            unsigned short h = f2bf(xr8[e]);
            ah[e] = (short)h;
            al[e] = (short)f2bf(xr8[e] - __uint_as_float((unsigned)h << 16));
        }
        #pragma unroll
        for (int ct = 0; ct < 4; ++ct)
            acc[ct] = __builtin_amdgcn_mfma_f32_16x16x32_bf16(ah, wh[ks][ct], acc[ct], 0, 0, 0);
        #pragma unroll
        for (int ct = 0; ct < 4; ++ct)
            acc[ct] = __builtin_amdgcn_mfma_f32_16x16x32_bf16(al, wh[ks][ct], acc[ct], 0, 0, 0);
        #pragma unroll
        for (int ct = 0; ct < 4; ++ct)
            acc[ct] = __builtin_amdgcn_mfma_f32_16x16x32_bf16(ah, wl[ks][ct], acc[ct], 0, 0, 0);
    }

    // --- epilogue: scale by dinv, pack bf16, store ---
    const int orow = row0 + khi * 4;
    #pragma unroll
    for (int r = 0; r < 4; ++r) {
        const float d = dinv[orow + r];
        #pragma unroll
        for (int ct = 0; ct < 4; ++ct)
            Hs[(size_t)(orow + r) * HID + ct * 16 + rlo] = f2bf(acc[ct][r] * d);
    }
}

// ---------------- gather1 + fused gemm2 ----------------
// EIGHTH-WAVE per node, uint4 (16B) lanes: 8 lanes cover the 128B row,
// 8 nodes/wave, 8 rows in flight each. W2 read from GLOBAL (L1-hot, 8KB):
// drops w2s LDS (29.5 -> 21.5 KB, 5 -> 7 blocks/CU) and removes the only
// __syncthreads -> waves fully independent. Zero-row padding: no predication.
__global__ __launch_bounds__(256) void k_gather1f(const int* __restrict__ offs,
                                                  const int* __restrict__ offsE,
                                                  const int* __restrict__ csr,
                                                  const float* __restrict__ dinv,
                                                  const unsigned short* __restrict__ Hs,
                                                  const float* __restrict__ b1,
                                                  const float* __restrict__ W2,
                                                  unsigned* __restrict__ H2u) {
    __shared__ int   sidx[4][8][100];          // 12.8 KB
    __shared__ float wrow[4][8][68];           // 8.7 KB
    const int t = threadIdx.x;
    // zero-row (index N) of H2u for k_gather2's padded gather
    if (blockIdx.x == 0 && t < OUTC / 2) H2u[(size_t)N * 16 + t] = 0u;

    const int wave = t >> 6, lane = t & 63, q = lane >> 3, c = lane & 7;
    const int myNode = blockIdx.x * 32 + wave * 8 + q;     // N % 32 == 0
    const int o0 = offs[myNode], o1 = offsE[myNode];
    const int deg  = o1 - o0;
    const int rdeg = (deg + 7) & ~7;
    for (int i = c; i < deg; i += 8) sidx[wave][q][i] = csr[o0 + i];
    if (c < rdeg - deg) sidx[wave][q][deg + c] = N;        // pad -> zero row

    const uint4* __restrict__ Hu4 = (const uint4*)Hs;      // row = 8 uint4
    const float dn = dinv[myNode];
    uint4 su = Hu4[(size_t)myNode * 8 + c];                // self loop (pre-scaled)
    float p0 = blo(su.x), p1 = bhi(su.x), p2 = blo(su.y), p3 = bhi(su.y);
    float p4 = blo(su.z), p5 = bhi(su.z), p6 = blo(su.w), p7 = bhi(su.w);
    float r0 = 0, r1 = 0, r2 = 0, r3 = 0, r4 = 0, r5 = 0, r6 = 0, r7 = 0;
    for (int k = 0; k < rdeg; k += 8) {
        int4 sa = *(const int4*)&sidx[wave][q][k];         // ds_read_b128
        int4 sb = *(const int4*)&sidx[wave][q][k + 4];     // ds_read_b128
        uint4 u0 = Hu4[(size_t)sa.x * 8 + c];
        uint4 u1 = Hu4[(size_t)sa.y * 8 + c];
        uint4 u2 = Hu4[(size_t)sa.z * 8 + c];
        uint4 u3 = Hu4[(size_t)sa.w * 8 + c];
        uint4 u4 = Hu4[(size_t)sb.x * 8 + c];
        uint4 u5 = Hu4[(size_t)sb.y * 8 + c];
        uint4 u6 = Hu4[(size_t)sb.z * 8 + c];
        uint4 u7 = Hu4[(size_t)sb.w * 8 + c];
        p0 += blo(u0.x); p1 += bhi(u0.x); p2 += blo(u0.y); p3 += bhi(u0.y);
        p4 += blo(u0.z); p5 += bhi(u0.z); p6 += blo(u0.w); p7 += bhi(u0.w);
        r0 += blo(u1.x); r1 += bhi(u1.x); r2 += blo(u1.y); r3 += bhi(u1.y);
        r4 += blo(u1.z); r5 += bhi(u1.z); r6 += blo(u1.w); r7 += bhi(u1.w);
        p0 += blo(u2.x); p1 += bhi(u2.x); p2 += blo(u2.y); p3 += bhi(u2.y);
        p4 += blo(u2.z); p5 += bhi(u2.z); p6 += blo(u2.w); p7 += bhi(u2.w);
        r0 += blo(u3.x); r1 += bhi(u3.x); r2 += blo(u3.y); r3 += bhi(u3.y);
        r4 += blo(u3.z); r5 += bhi(u3.z); r6 += blo(u3.w); r7 += bhi(u3.w);
        p0 += blo(u4.x); p1 += bhi(u4.x); p2 += blo(u4.y); p3 += bhi(u4.y);
        p4 += blo(u4.z); p5 += bhi(u4.z); p6 += blo(u4.w); p7 += bhi(u4.w);
        r0 += blo(u5.x); r1 += bhi(u5.x); r2 += blo(u5.y); r3 += bhi(u5.y);
        r4 += blo(u5.z); r5 += bhi(u5.z); r6 += blo(u5.w); r7 += bhi(u5.w);
        p0 += blo(u6.x); p1 += bhi(u6.x); p2 += blo(u6.y); p3 += bhi(u6.y);
        p4 += blo(u6.z); p5 += bhi(u6.z); p6 += blo(u6.w); p7 += bhi(u6.w);
        r0 += blo(u7.x); r1 += bhi(u7.x); r2 += blo(u7.y); r3 += bhi(u7.y);
        r4 += blo(u7.z); r5 += bhi(u7.z); r6 += blo(u7.w); r7 += bhi(u7.w);
    }
    float s0 = p0 + r0, s1 = p1 + r1, s2 = p2 + r2, s3 = p3 + r3;
    float s4 = p4 + r4, s5 = p5 + r5, s6 = p6 + r6, s7 = p7 + r7;
    float4 ba = *(const float4*)(b1 + 8 * c);
    float4 bbv = *(const float4*)(b1 + 8 * c + 4);
    float4 wv0, wv1;
    wv0.x = fmaxf(s0 * dn + ba.x, 0.0f);                   // fused relu+bias
    wv0.y = fmaxf(s1 * dn + ba.y, 0.0f);
    wv0.z = fmaxf(s2 * dn + ba.z, 0.0f);
    wv0.w = fmaxf(s3 * dn + ba.w, 0.0f);
    wv1.x = fmaxf(s4 * dn + bbv.x, 0.0f);
    wv1.y = fmaxf(s5 * dn + bbv.y, 0.0f);
    wv1.z = fmaxf(s6 * dn + bbv.z, 0.0f);
    wv1.w = fmaxf(s7 * dn + bbv.w, 0.0f);
    *(float4*)&wrow[wave][q][8 * c]     = wv0;
    *(float4*)&wrow[wave][q][8 * c + 4] = wv1;

    // fused gemm2: lane c computes outputs 4c..4c+3 of ITS node (no shuffle);
    // W2 columns read straight from global (L1-hot; same values as old w2s copy)
    const float4* __restrict__ W2v = (const float4*)W2;    // row = 8 float4
    float4 acc = {0, 0, 0, 0};
    #pragma unroll
    for (int k = 0; k < HID; k += 4) {
        float4 wr = *(const float4*)&wrow[wave][q][k];
        float4 wa = W2v[(k + 0) * 8 + c];
        float4 wb = W2v[(k + 1) * 8 + c];
        float4 wc = W2v[(k + 2) * 8 + c];
        float4 wd = W2v[(k + 3) * 8 + c];
        acc.x += wr.x * wa.x + wr.y * wb.x + wr.z * wc.x + wr.w * wd.x;
        acc.y += wr.x * wa.y + wr.y * wb.y + wr.z * wc.y + wr.w * wd.y;
        acc.z += wr.x * wa.z + wr.y * wb.z + wr.z * wc.z + wr.w * wd.z;
        acc.w += wr.x * wa.w + wr.y * wb.w + wr.z * wc.w + wr.w * wd.w;
    }
    uint2 hw;
    hw.x = (unsigned)f2bf(acc.x * dn) | ((unsigned)f2bf(acc.y * dn) << 16);
    hw.y = (unsigned)f2bf(acc.z * dn) | ((unsigned)f2bf(acc.w * dn) << 16);
    ((uint2*)H2u)[(size_t)myNode * 8 + c] = hw;
}

// ---------------- gather2: SIXTEENTH-WAVE per node, uint4 lanes ----------------
// 4 lanes cover the 64B row, 16 nodes/wave, 8 rows in flight each.
__global__ __launch_bounds__(256) void k_gather2(const int* __restrict__ offs,
                                                 const int* __restrict__ offsE,
                                                 const int* __restrict__ csr,
                                                 const float* __restrict__ dinv,
                                                 const unsigned* __restrict__ H2u,
                                                 const float* __restrict__ b2,
                                                 float* __restrict__ out) {
    __shared__ int sidx[4][16][100];           // 25.6 KB
    const int t = threadIdx.x;
    const int wave = t >> 6, lane = t & 63, q = lane >> 2, c = lane & 3;
    const int myNode = blockIdx.x * 64 + wave * 16 + q;    // grid = ceil(N/64)
    if (myNode >= N) return;                   // guard BEFORE staging (tail block)
    const int o0 = offs[myNode], o1 = offsE[myNode];
    const int deg  = o1 - o0;
    const int rdeg = (deg + 7) & ~7;
    for (int i = c; i < deg; i += 4) sidx[wave][q][i] = csr[o0 + i];
    for (int i = deg + c; i < rdeg; i += 4) sidx[wave][q][i] = N;  // pad -> zero row

    const uint4* __restrict__ H4 = (const uint4*)H2u;      // row = 4 uint4
    const float dn = dinv[myNode];
    uint4 su = H4[(size_t)myNode * 4 + c];                 // self loop (pre-scaled)
    float p0 = blo(su.x), p1 = bhi(su.x), p2 = blo(su.y), p3 = bhi(su.y);
    float p4 = blo(su.z), p5 = bhi(su.z), p6 = blo(su.w), p7 = bhi(su.w);
    float r0 = 0, r1 = 0, r2 = 0, r3 = 0, r4 = 0, r5 = 0, r6 = 0, r7 = 0;
    for (int k = 0; k < rdeg; k += 8) {
        int4 sa = *(const int4*)&sidx[wave][q][k];         // ds_read_b128
        int4 sb = *(const int4*)&sidx[wave][q][k + 4];     // ds_read_b128
        uint4 u0 = H4[(size_t)sa.x * 4 + c];
        uint4 u1 = H4[(size_t)sa.y * 4 + c];
        uint4 u2 = H4[(size_t)sa.z * 4 + c];
        uint4 u3 = H4[(size_t)sa.w * 4 + c];
        uint4 u4 = H4[(size_t)sb.x * 4 + c];
        uint4 u5 = H4[(size_t)sb.y * 4 + c];
        uint4 u6 = H4[(size_t)sb.z * 4 + c];
        uint4 u7 = H4[(size_t)sb.w * 4 + c];
        p0 += blo(u0.x); p1 += bhi(u0.x); p2 += blo(u0.y); p3 += bhi(u0.y);
        p4 += blo(u0.z); p5 += bhi(u0.z); p6 += blo(u0.w); p7 += bhi(u0.w);
        r0 += blo(u1.x); r1 += bhi(u1.x); r2 += blo(u1.y); r3 += bhi(u1.y);
        r4 += blo(u1.z); r5 += bhi(u1.z); r6 += blo(u1.w); r7 += bhi(u1.w);
        p0 += blo(u2.x); p1 += bhi(u2.x); p2 += blo(u2.y); p3 += bhi(u2.y);
        p4 += blo(u2.z); p5 += bhi(u2.z); p6 += blo(u2.w); p7 += bhi(u2.w);
        r0 += blo(u3.x); r1 += bhi(u3.x); r2 += blo(u3.y); r3 += bhi(u3.y);
        r4 += blo(u3.z); r5 += bhi(u3.z); r6 += blo(u3.w); r7 += bhi(u3.w);
        p0 += blo(u4.x); p1 += bhi(u4.x); p2 += blo(u4.y); p3 += bhi(u4.y);
        p4 += blo(u4.z); p5 += bhi(u4.z); p6 += blo(u4.w); p7 += bhi(u4.w);
        r0 += blo(u5.x); r1 += bhi(u5.x); r2 += blo(u5.y); r3 += bhi(u5.y);
        r4 += blo(u5.z); r5 += bhi(u5.z); r6 += blo(u5.w); r7 += bhi(u5.w);
        p0 += blo(u6.x); p1 += bhi(u6.x); p2 += blo(u6.y); p3 += bhi(u6.y);
        p4 += blo(u6.z); p5 += bhi(u6.z); p6 += blo(u6.w); p7 += bhi(u6.w);
        r0 += blo(u7.x); r1 += bhi(u7.x); r2 += blo(u7.y); r3 += bhi(u7.y);
        r4 += blo(u7.z); r5 += bhi(u7.z); r6 += blo(u7.w); r7 += bhi(u7.w);
    }
    float s0 = p0 + r0, s1 = p1 + r1, s2 = p2 + r2, s3 = p3 + r3;
    float s4 = p4 + r4, s5 = p5 + r5, s6 = p6 + r6, s7 = p7 + r7;
    float4 ba = *(const float4*)(b2 + 8 * c);
    float4 bbv = *(const float4*)(b2 + 8 * c + 4);
    float4 o0v, o1v;
    o0v.x = s0 * dn + ba.x;  o0v.y = s1 * dn + ba.y;
    o0v.z = s2 * dn + ba.z;  o0v.w = s3 * dn + ba.w;
    o1v.x = s4 * dn + bbv.x; o1v.y = s5 * dn + bbv.y;
    o1v.z = s6 * dn + bbv.z; o1v.w = s7 * dn + bbv.w;
    float* op = out + (size_t)myNode * OUTC + 8 * c;
    *(float4*)op       = o0v;                              // 128B/node, coalesced
    *(float4*)(op + 4) = o1v;
}

extern "C" void kernel_launch(void* const* d_in, const int* in_sizes, int n_in,
                              void* d_out, int out_size, void* d_ws, size_t ws_size,
                              hipStream_t stream) {
    const float* x   = (const float*)d_in[0];
    const int*   ei  = (const int*)d_in[1];
    const float* W1  = (const float*)d_in[2];
    const float* b1  = (const float*)d_in[3];
    const float* W2  = (const float*)d_in[4];
    const float* b2  = (const float*)d_in[5];
    float*       out = (float*)d_out;

    const int* srcp = ei;
    const int* dstp = ei + E;

    char* ws = (char*)d_ws;
    int*            cursor = (int*)(ws + 0);                   // 784 B
    int*            offs   = (int*)(ws + (64u << 10));         // 400 KB
    int*            offsE  = (int*)(ws + (512u << 10));        // 400 KB
    float*          dinv   = (float*)(ws + (960u << 10));      // 400 KB
    unsigned*       packed = (unsigned*)(ws + (1536u << 10));  // 7.23 MB (csr in place)
    unsigned short* Hs     = (unsigned short*)(ws + (9u << 20));   // 12.8 MB + zero row
    unsigned*       H2u    = (unsigned*)(ws + (22u << 20));    // 6.4 MB + zero row
    int*            csr    = (int*)packed;

    hipMemsetAsync(cursor, 0, NB * sizeof(int), stream);
    k_part <<<PB, 256, 0, stream>>>(srcp, dstp, cursor, packed);
    k_build<<<NB, 512, 0, stream>>>(cursor, packed, offs, offsE, dinv);

    k_gemm1   <<<(N / 16 + 3) / 4, 256, 0, stream>>>(x, W1, dinv, Hs);
    k_gather1f<<<N / 32, 256, 0, stream>>>(offs, offsE, csr, dinv, Hs, b1, W2, H2u);
    k_gather2 <<<(N + 63) / 64, 256, 0, stream>>>(offs, offsE, csr, dinv, H2u, b2, out);
}

// Round 11
// 205.995 us; speedup vs baseline: 1.2050x; 1.0515x over previous
//
#include <hip/hip_runtime.h>

constexpr int N  = 100000;
constexpr int E  = 1600000;
constexpr int IN = 128, HID = 64, OUTC = 32;

// coarse radix partition params
constexpr int SHIFT = 9;                       // 512 nodes per bucket
constexpr int NPB   = 1 << SHIFT;              // 512
constexpr int NB    = (N + NPB - 1) / NPB;     // 196 buckets
constexpr int CAP   = 16384;                   // LDS stage cap
constexpr int CAPB  = 9216;                    // fixed bucket stride (mean 8192, +11 sigma)
constexpr int PB    = 800;                     // partition blocks (3 blocks/CU)
constexpr int CHUNK = E / PB;                  // 2000 (exact)

typedef __attribute__((ext_vector_type(8))) short bf16x8_t;  // 8 bf16 (4 VGPR)
typedef __attribute__((ext_vector_type(4))) float f32x4_t;   // 4 fp32

// ---- bf16 helpers ----
__device__ __forceinline__ unsigned short f2bf(float f) {
    union { float f; unsigned int u; } v; v.f = f;
    unsigned int u = v.u;
    return (unsigned short)((u + 0x7fffu + ((u >> 16) & 1u)) >> 16);
}
__device__ __forceinline__ float blo(unsigned u) { return __uint_as_float(u << 16); }
__device__ __forceinline__ float bhi(unsigned u) { return __uint_as_float(u & 0xffff0000u); }

// ---------------- partition edges into FIXED-STRIDE coarse buckets ----------------
// Bucket b owns packed[b*CAPB .. b*CAPB+CAPB); blocks reserve ranges via
// atomicAdd on cursor[b] (zeroed by a tiny memset). Replaces k_hist + k_bscan.
__global__ __launch_bounds__(256) void k_part(const int* __restrict__ src,
                                              const int* __restrict__ dst,
                                              int* __restrict__ cursor,
                                              unsigned* __restrict__ packed) {
    __shared__ int lh[NB], lb[NB], lc[NB];
    const int t = threadIdx.x;
    const int beg = blockIdx.x * CHUNK, end = beg + CHUNK;
    for (int i = t; i < NB; i += 256) lh[i] = 0;
    __syncthreads();
    for (int e = beg + t; e < end; e += 256) atomicAdd(&lh[dst[e] >> SHIFT], 1);
    __syncthreads();
    for (int i = t; i < NB; i += 256) {
        lb[i] = lh[i] ? (i * CAPB + atomicAdd(&cursor[i], lh[i])) : 0;
        lc[i] = 0;
    }
    __syncthreads();
    for (int e = beg + t; e < end; e += 256) {
        int d = dst[e], b = d >> SHIFT;
        int idx = atomicAdd(&lc[b], 1);
        packed[lb[b] + idx] = ((unsigned)(d & (NPB - 1)) << 17) | (unsigned)src[e];
    }
}

// ---------------- per-bucket CSR build: offs/offsEnd + dinv + in-place sorted csr ----------------
__global__ __launch_bounds__(512) void k_build(const int* __restrict__ cursor,
                                               unsigned* __restrict__ packed,
                                               int* __restrict__ offs,
                                               int* __restrict__ offsE,
                                               float* __restrict__ dinv) {
    __shared__ int cnt[NPB];
    __shared__ unsigned stage[CAP];            // 64 KB
    const int t = threadIdx.x, b = blockIdx.x;
    const int base = b * CAPB, cntE = cursor[b];
    const int node0 = b << SHIFT;
    cnt[t] = 0;
    __syncthreads();
    for (int i = t; i < cntE; i += 512) atomicAdd(&cnt[packed[base + i] >> 17], 1);
    __syncthreads();
    const int v = cnt[t];
    __syncthreads();
    for (int off = 1; off < NPB; off <<= 1) {
        int x = (t >= off) ? cnt[t - off] : 0;
        __syncthreads();
        cnt[t] += x;
        __syncthreads();
    }
    const int ex = cnt[t] - v;
    const int node = node0 + t;
    if (node < N) {
        offs[node]  = base + ex;
        offsE[node] = base + ex + v;
        dinv[node]  = rsqrtf((float)v + 1.0f); // +1 self loop
    }
    __syncthreads();
    cnt[t] = ex;
    __syncthreads();
    for (int i = t; i < cntE; i += 512) {
        unsigned p = packed[base + i];
        int idx = atomicAdd(&cnt[p >> 17], 1);
        if (idx < CAP) stage[idx] = p & 0x1FFFFu;
    }
    __syncthreads();
    for (int i = t; i < cntE; i += 512)
        packed[base + i] = stage[i];           // in-place: csr == packed buffer
}

// ---------------- GEMM1 via split-bf16 MFMA: Hs = bf16(dinv[row] * (X @ W1)) ----------------
// x = xh + xl, w = wh + wl (bf16 each); X@W ~= xh wh + xl wh + xh wl; fp32 acc.
// 256-thread blocks, ONE 16-row tile per wave -> 6250 independent waves.
__global__ __launch_bounds__(256, 4) void k_gemm1(const float* __restrict__ X,
                                                  const float* __restrict__ W,
                                                  const float* __restrict__ dinv,
                                                  unsigned short* __restrict__ Hs) {
    const int t = threadIdx.x;
    // zero-row (index N) for the padded gathers
    if (blockIdx.x == 0 && t < HID / 2)
        ((unsigned*)(Hs + (size_t)N * HID))[t] = 0u;

    const int wave = t >> 6, l = t & 63;
    const int rlo  = l & 15, khi = l >> 4;     // khi in 0..3
    const int row0 = (blockIdx.x * 4 + wave) * 16;
    if (row0 >= N) return;                     // tail tiles (N % 16 == 0)

    // --- issue A-tile loads first (latency hides under W-prep) ---
    const float* xr = X + (size_t)(row0 + rlo) * IN + khi * 8;
    float4 xa[4], xb[4];
    #pragma unroll
    for (int ks = 0; ks < 4; ++ks) {
        xa[ks] = *(const float4*)(xr + ks * 32);
        xb[ks] = *(const float4*)(xr + ks * 32 + 4);
    }

    // --- W fragments, split hi/lo: 4 k-steps x 4 col-tiles ---
    bf16x8_t wh[4][4], wl[4][4];
    #pragma unroll
    for (int ks = 0; ks < 4; ++ks) {
        #pragma unroll
        for (int ct = 0; ct < 4; ++ct) {
            const float* wp = W + (ks * 32 + khi * 8) * HID + ct * 16 + rlo;
            #pragma unroll
            for (int e = 0; e < 8; ++e) {
                float w = wp[e * HID];
                unsigned short h = f2bf(w);
                float r = w - __uint_as_float((unsigned)h << 16);
                wh[ks][ct][e] = (short)h;
                wl[ks][ct][e] = (short)f2bf(r);
            }
        }
    }

    f32x4_t acc[4] = {{0,0,0,0},{0,0,0,0},{0,0,0,0},{0,0,0,0}};
    #pragma unroll
    for (int ks = 0; ks < 4; ++ks) {
        float xr8[8] = {xa[ks].x, xa[ks].y, xa[ks].z, xa[ks].w,
                        xb[ks].x, xb[ks].y, xb[ks].z, xb[ks].w};
        bf16x8_t ah, al;
        #pragma unroll
        for (int e = 0; e < 8; ++e) {
            unsigned short h = f2bf(xr8[e]);
            ah[e] = (short)h;
            al[e] = (short)f2bf(xr8[e] - __uint_as_float((unsigned)h << 16));
        }
        #pragma unroll
        for (int ct = 0; ct < 4; ++ct)
            acc[ct] = __builtin_amdgcn_mfma_f32_16x16x32_bf16(ah, wh[ks][ct], acc[ct], 0, 0, 0);
        #pragma unroll
        for (int ct = 0; ct < 4; ++ct)
            acc[ct] = __builtin_amdgcn_mfma_f32_16x16x32_bf16(al, wh[ks][ct], acc[ct], 0, 0, 0);
        #pragma unroll
        for (int ct = 0; ct < 4; ++ct)
            acc[ct] = __builtin_amdgcn_mfma_f32_16x16x32_bf16(ah, wl[ks][ct], acc[ct], 0, 0, 0);
    }

    // --- epilogue: scale by dinv, pack bf16, store ---
    const int orow = row0 + khi * 4;
    #pragma unroll
    for (int r = 0; r < 4; ++r) {
        const float d = dinv[orow + r];
        #pragma unroll
        for (int ct = 0; ct < 4; ++ct)
            Hs[(size_t)(orow + r) * HID + ct * 16 + rlo] = f2bf(acc[ct][r] * d);
    }
}

// ---------------- gather1 + fused gemm2 ----------------
// EIGHTH-WAVE per node, uint4 (16B) lanes. W2 staged in LDS (w2s): R10's
// W2-from-global regressed gather1f 41->46us (64 global loads/thread in the
// gemm2 tail queued behind the gather's latency-critical Hs loads in the same
// vmcnt pipe). LDS broadcast reads keep the global pipe gather-only.
__global__ __launch_bounds__(256) void k_gather1f(const int* __restrict__ offs,
                                                  const int* __restrict__ offsE,
                                                  const int* __restrict__ csr,
                                                  const float* __restrict__ dinv,
                                                  const unsigned short* __restrict__ Hs,
                                                  const float* __restrict__ b1,
                                                  const float* __restrict__ W2,
                                                  unsigned* __restrict__ H2u) {
    __shared__ float w2s[HID * OUTC];          // 8 KB
    __shared__ int   sidx[4][8][100];          // 12.8 KB
    __shared__ float wrow[4][8][68];           // 8.7 KB
    const int t = threadIdx.x;
    // zero-row (index N) of H2u for k_gather2's padded gather
    if (blockIdx.x == 0 && t < OUTC / 2) H2u[(size_t)N * 16 + t] = 0u;
    for (int i = t; i < HID * OUTC / 4; i += 256)
        ((float4*)w2s)[i] = ((const float4*)W2)[i];
    __syncthreads();

    const int wave = t >> 6, lane = t & 63, q = lane >> 3, c = lane & 7;
    const int myNode = blockIdx.x * 32 + wave * 8 + q;     // N % 32 == 0
    const int o0 = offs[myNode], o1 = offsE[myNode];
    const int deg  = o1 - o0;
    const int rdeg = (deg + 7) & ~7;
    for (int i = c; i < deg; i += 8) sidx[wave][q][i] = csr[o0 + i];
    if (c < rdeg - deg) sidx[wave][q][deg + c] = N;        // pad -> zero row

    const uint4* __restrict__ Hu4 = (const uint4*)Hs;      // row = 8 uint4
    const float dn = dinv[myNode];
    uint4 su = Hu4[(size_t)myNode * 8 + c];                // self loop (pre-scaled)
    float p0 = blo(su.x), p1 = bhi(su.x), p2 = blo(su.y), p3 = bhi(su.y);
    float p4 = blo(su.z), p5 = bhi(su.z), p6 = blo(su.w), p7 = bhi(su.w);
    float r0 = 0, r1 = 0, r2 = 0, r3 = 0, r4 = 0, r5 = 0, r6 = 0, r7 = 0;
    for (int k = 0; k < rdeg; k += 8) {
        int4 sa = *(const int4*)&sidx[wave][q][k];         // ds_read_b128
        int4 sb = *(const int4*)&sidx[wave][q][k + 4];     // ds_read_b128
        uint4 u0 = Hu4[(size_t)sa.x * 8 + c];
        uint4 u1 = Hu4[(size_t)sa.y * 8 + c];
        uint4 u2 = Hu4[(size_t)sa.z * 8 + c];
        uint4 u3 = Hu4[(size_t)sa.w * 8 + c];
        uint4 u4 = Hu4[(size_t)sb.x * 8 + c];
        uint4 u5 = Hu4[(size_t)sb.y * 8 + c];
        uint4 u6 = Hu4[(size_t)sb.z * 8 + c];
        uint4 u7 = Hu4[(size_t)sb.w * 8 + c];
        p0 += blo(u0.x); p1 += bhi(u0.x); p2 += blo(u0.y); p3 += bhi(u0.y);
        p4 += blo(u0.z); p5 += bhi(u0.z); p6 += blo(u0.w); p7 += bhi(u0.w);
        r0 += blo(u1.x); r1 += bhi(u1.x); r2 += blo(u1.y); r3 += bhi(u1.y);
        r4 += blo(u1.z); r5 += bhi(u1.z); r6 += blo(u1.w); r7 += bhi(u1.w);
        p0 += blo(u2.x); p1 += bhi(u2.x); p2 += blo(u2.y); p3 += bhi(u2.y);
        p4 += blo(u2.z); p5 += bhi(u2.z); p6 += blo(u2.w); p7 += bhi(u2.w);
        r0 += blo(u3.x); r1 += bhi(u3.x); r2 += blo(u3.y); r3 += bhi(u3.y);
        r4 += blo(u3.z); r5 += bhi(u3.z); r6 += blo(u3.w); r7 += bhi(u3.w);
        p0 += blo(u4.x); p1 += bhi(u4.x); p2 += blo(u4.y); p3 += bhi(u4.y);
        p4 += blo(u4.z); p5 += bhi(u4.z); p6 += blo(u4.w); p7 += bhi(u4.w);
        r0 += blo(u5.x); r1 += bhi(u5.x); r2 += blo(u5.y); r3 += bhi(u5.y);
        r4 += blo(u5.z); r5 += bhi(u5.z); r6 += blo(u5.w); r7 += bhi(u5.w);
        p0 += blo(u6.x); p1 += bhi(u6.x); p2 += blo(u6.y); p3 += bhi(u6.y);
        p4 += blo(u6.z); p5 += bhi(u6.z); p6 += blo(u6.w); p7 += bhi(u6.w);
        r0 += blo(u7.x); r1 += bhi(u7.x); r2 += blo(u7.y); r3 += bhi(u7.y);
        r4 += blo(u7.z); r5 += bhi(u7.z); r6 += blo(u7.w); r7 += bhi(u7.w);
    }
    float s0 = p0 + r0, s1 = p1 + r1, s2 = p2 + r2, s3 = p3 + r3;
    float s4 = p4 + r4, s5 = p5 + r5, s6 = p6 + r6, s7 = p7 + r7;
    float4 ba = *(const float4*)(b1 + 8 * c);
    float4 bbv = *(const float4*)(b1 + 8 * c + 4);
    float4 wv0, wv1;
    wv0.x = fmaxf(s0 * dn + ba.x, 0.0f);                   // fused relu+bias
    wv0.y = fmaxf(s1 * dn + ba.y, 0.0f);
    wv0.z = fmaxf(s2 * dn + ba.z, 0.0f);
    wv0.w = fmaxf(s3 * dn + ba.w, 0.0f);
    wv1.x = fmaxf(s4 * dn + bbv.x, 0.0f);
    wv1.y = fmaxf(s5 * dn + bbv.y, 0.0f);
    wv1.z = fmaxf(s6 * dn + bbv.z, 0.0f);
    wv1.w = fmaxf(s7 * dn + bbv.w, 0.0f);
    *(float4*)&wrow[wave][q][8 * c]     = wv0;
    *(float4*)&wrow[wave][q][8 * c + 4] = wv1;

    // fused gemm2: lane c computes outputs 4c..4c+3 of ITS node (no shuffle);
    // W2 columns from LDS (broadcast, conflict-free)
    float4 acc = {0, 0, 0, 0};
    #pragma unroll
    for (int k = 0; k < HID; k += 4) {
        float4 wr = *(const float4*)&wrow[wave][q][k];
        float4 wa = *(const float4*)&w2s[(k + 0) * OUTC + 4 * c];
        float4 wb = *(const float4*)&w2s[(k + 1) * OUTC + 4 * c];
        float4 wc = *(const float4*)&w2s[(k + 2) * OUTC + 4 * c];
        float4 wd = *(const float4*)&w2s[(k + 3) * OUTC + 4 * c];
        acc.x += wr.x * wa.x + wr.y * wb.x + wr.z * wc.x + wr.w * wd.x;
        acc.y += wr.x * wa.y + wr.y * wb.y + wr.z * wc.y + wr.w * wd.y;
        acc.z += wr.x * wa.z + wr.y * wb.z + wr.z * wc.z + wr.w * wd.z;
        acc.w += wr.x * wa.w + wr.y * wb.w + wr.z * wc.w + wr.w * wd.w;
    }
    uint2 hw;
    hw.x = (unsigned)f2bf(acc.x * dn) | ((unsigned)f2bf(acc.y * dn) << 16);
    hw.y = (unsigned)f2bf(acc.z * dn) | ((unsigned)f2bf(acc.w * dn) << 16);
    ((uint2*)H2u)[(size_t)myNode * 8 + c] = hw;
}

// ---------------- gather2: SIXTEENTH-WAVE per node, uint4 lanes ----------------
__global__ __launch_bounds__(256) void k_gather2(const int* __restrict__ offs,
                                                 const int* __restrict__ offsE,
                                                 const int* __restrict__ csr,
                                                 const float* __restrict__ dinv,
                                                 const unsigned* __restrict__ H2u,
                                                 const float* __restrict__ b2,
                                                 float* __restrict__ out) {
    __shared__ int sidx[4][16][100];           // 25.6 KB
    const int t = threadIdx.x;
    const int wave = t >> 6, lane = t & 63, q = lane >> 2, c = lane & 3;
    const int myNode = blockIdx.x * 64 + wave * 16 + q;    // grid = ceil(N/64)
    if (myNode >= N) return;                   // guard BEFORE staging (tail block)
    const int o0 = offs[myNode], o1 = offsE[myNode];
    const int deg  = o1 - o0;
    const int rdeg = (deg + 7) & ~7;
    for (int i = c; i < deg; i += 4) sidx[wave][q][i] = csr[o0 + i];
    for (int i = deg + c; i < rdeg; i += 4) sidx[wave][q][i] = N;  // pad -> zero row

    const uint4* __restrict__ H4 = (const uint4*)H2u;      // row = 4 uint4
    const float dn = dinv[myNode];
    uint4 su = H4[(size_t)myNode * 4 + c];                 // self loop (pre-scaled)
    float p0 = blo(su.x), p1 = bhi(su.x), p2 = blo(su.y), p3 = bhi(su.y);
    float p4 = blo(su.z), p5 = bhi(su.z), p6 = blo(su.w), p7 = bhi(su.w);
    float r0 = 0, r1 = 0, r2 = 0, r3 = 0, r4 = 0, r5 = 0, r6 = 0, r7 = 0;
    for (int k = 0; k < rdeg; k += 8) {
        int4 sa = *(const int4*)&sidx[wave][q][k];         // ds_read_b128
        int4 sb = *(const int4*)&sidx[wave][q][k + 4];     // ds_read_b128
        uint4 u0 = H4[(size_t)sa.x * 4 + c];
        uint4 u1 = H4[(size_t)sa.y * 4 + c];
        uint4 u2 = H4[(size_t)sa.z * 4 + c];
        uint4 u3 = H4[(size_t)sa.w * 4 + c];
        uint4 u4 = H4[(size_t)sb.x * 4 + c];
        uint4 u5 = H4[(size_t)sb.y * 4 + c];
        uint4 u6 = H4[(size_t)sb.z * 4 + c];
        uint4 u7 = H4[(size_t)sb.w * 4 + c];
        p0 += blo(u0.x); p1 += bhi(u0.x); p2 += blo(u0.y); p3 += bhi(u0.y);
        p4 += blo(u0.z); p5 += bhi(u0.z); p6 += blo(u0.w); p7 += bhi(u0.w);
        r0 += blo(u1.x); r1 += bhi(u1.x); r2 += blo(u1.y); r3 += bhi(u1.y);
        r4 += blo(u1.z); r5 += bhi(u1.z); r6 += blo(u1.w); r7 += bhi(u1.w);
        p0 += blo(u2.x); p1 += bhi(u2.x); p2 += blo(u2.y); p3 += bhi(u2.y);
        p4 += blo(u2.z); p5 += bhi(u2.z); p6 += blo(u2.w); p7 += bhi(u2.w);
        r0 += blo(u3.x); r1 += bhi(u3.x); r2 += blo(u3.y); r3 += bhi(u3.y);
        r4 += blo(u3.z); r5 += bhi(u3.z); r6 += blo(u3.w); r7 += bhi(u3.w);
        p0 += blo(u4.x); p1 += bhi(u4.x); p2 += blo(u4.y); p3 += bhi(u4.y);
        p4 += blo(u4.z); p5 += bhi(u4.z); p6 += blo(u4.w); p7 += bhi(u4.w);
        r0 += blo(u5.x); r1 += bhi(u5.x); r2 += blo(u5.y); r3 += bhi(u5.y);
        r4 += blo(u5.z); r5 += bhi(u5.z); r6 += blo(u5.w); r7 += bhi(u5.w);
        p0 += blo(u6.x); p1 += bhi(u6.x); p2 += blo(u6.y); p3 += bhi(u6.y);
        p4 += blo(u6.z); p5 += bhi(u6.z); p6 += blo(u6.w); p7 += bhi(u6.w);
        r0 += blo(u7.x); r1 += bhi(u7.x); r2 += blo(u7.y); r3 += bhi(u7.y);
        r4 += blo(u7.z); r5 += bhi(u7.z); r6 += blo(u7.w); r7 += bhi(u7.w);
    }
    float s0 = p0 + r0, s1 = p1 + r1, s2 = p2 + r2, s3 = p3 + r3;
    float s4 = p4 + r4, s5 = p5 + r5, s6 = p6 + r6, s7 = p7 + r7;
    float4 ba = *(const float4*)(b2 + 8 * c);
    float4 bbv = *(const float4*)(b2 + 8 * c + 4);
    float4 o0v, o1v;
    o0v.x = s0 * dn + ba.x;  o0v.y = s1 * dn + ba.y;
    o0v.z = s2 * dn + ba.z;  o0v.w = s3 * dn + ba.w;
    o1v.x = s4 * dn + bbv.x; o1v.y = s5 * dn + bbv.y;
    o1v.z = s6 * dn + bbv.z; o1v.w = s7 * dn + bbv.w;
    float* op = out + (size_t)myNode * OUTC + 8 * c;
    *(float4*)op       = o0v;                              // 128B/node, coalesced
    *(float4*)(op + 4) = o1v;
}

extern "C" void kernel_launch(void* const* d_in, const int* in_sizes, int n_in,
                              void* d_out, int out_size, void* d_ws, size_t ws_size,
                              hipStream_t stream) {
    const float* x   = (const float*)d_in[0];
    const int*   ei  = (const int*)d_in[1];
    const float* W1  = (const float*)d_in[2];
    const float* b1  = (const float*)d_in[3];
    const float* W2  = (const float*)d_in[4];
    const float* b2  = (const float*)d_in[5];
    float*       out = (float*)d_out;

    const int* srcp = ei;
    const int* dstp = ei + E;

    char* ws = (char*)d_ws;
    int*            cursor = (int*)(ws + 0);                   // 784 B
    int*            offs   = (int*)(ws + (64u << 10));         // 400 KB
    int*            offsE  = (int*)(ws + (512u << 10));        // 400 KB
    float*          dinv   = (float*)(ws + (960u << 10));      // 400 KB
    unsigned*       packed = (unsigned*)(ws + (1536u << 10));  // 7.23 MB (csr in place)
    unsigned short* Hs     = (unsigned short*)(ws + (9u << 20));   // 12.8 MB + zero row
    unsigned*       H2u    = (unsigned*)(ws + (22u << 20));    // 6.4 MB + zero row
    int*            csr    = (int*)packed;

    hipMemsetAsync(cursor, 0, NB * sizeof(int), stream);
    k_part <<<PB, 256, 0, stream>>>(srcp, dstp, cursor, packed);
    k_build<<<NB, 512, 0, stream>>>(cursor, packed, offs, offsE, dinv);

    k_gemm1   <<<(N / 16 + 3) / 4, 256, 0, stream>>>(x, W1, dinv, Hs);
    k_gather1f<<<N / 32, 256, 0, stream>>>(offs, offsE, csr, dinv, Hs, b1, W2, H2u);
    k_gather2 <<<(N + 63) / 64, 256, 0, stream>>>(offs, offsE, csr, dinv, H2u, b2, out);
}